// Round 2
// baseline (429.043 us; speedup 1.0000x reference)
//
#include <hip/hip_runtime.h>

// Problem constants (from reference setup_inputs)
#define B_   4
#define T_   1024
#define E_   4
#define C_   512
#define IN_  2048
#define OUT_ 8192
#define EI_  512   // expert in-features = IN_/E_

typedef float f32x4 __attribute__((ext_vector_type(4)));
typedef __bf16 bf16x8 __attribute__((ext_vector_type(8)));
typedef unsigned short ushort8 __attribute__((ext_vector_type(8)));

__device__ __forceinline__ unsigned short f32_bf16(float f) {
  unsigned int u = __float_as_uint(f);
  u += 0x7FFFu + ((u >> 16) & 1u);   // round-to-nearest-even (finite inputs)
  return (unsigned short)(u >> 16);
}

__device__ __forceinline__ void gl2lds16(const void* g, void* l) {
  __builtin_amdgcn_global_load_lds(
      (const __attribute__((address_space(1))) void*)g,
      (__attribute__((address_space(3))) void*)l, 16, 0, 0);
}

// ---------------------------------------------------------------------------
// Fused transpose-convert for x AND mask: src (B,T,2048) fp32 -> (B,4,512,T) bf16.
// Write phase: quad (u&3) covers 32 consecutive t per store -> 64B coalesced.
// ---------------------------------------------------------------------------
__global__ __launch_bounds__(256)
void transpose_cvt2(const float* __restrict__ xsrc, const float* __restrict__ msrc,
                    unsigned short* __restrict__ xdst, unsigned short* __restrict__ mdst) {
  __shared__ float tile[64][65];   // stride 65: write-read both ~2-way (free)
  const int which = blockIdx.z >> 2;
  const int b = blockIdx.z & 3;
  const float* src = which ? msrc : xsrc;
  unsigned short* dst = which ? mdst : xdst;
  const int k0 = blockIdx.x * 64;
  const int t0 = blockIdx.y * 64;
  const int u = threadIdx.x;
  const int lrow = u >> 4;          // t-local (x4 over r)
  const int lcol = (u & 15) * 4;    // k-local
  const float* s = src + (size_t)b * (T_ * 2048) + (size_t)t0 * 2048 + k0;
#pragma unroll
  for (int r = 0; r < 4; r++) {
    float4 v = *(const float4*)(s + (size_t)(lrow + 16 * r) * 2048 + lcol);
    tile[lrow + 16 * r][lcol]     = v.x;
    tile[lrow + 16 * r][lcol + 1] = v.y;
    tile[lrow + 16 * r][lcol + 2] = v.z;
    tile[lrow + 16 * r][lcol + 3] = v.w;
  }
  __syncthreads();
  const int kr = u >> 2;            // k-local row 0..63
  const int tq = (u & 3) * 8;       // t-offset within 32-t group
  const int kg = k0 + kr;
  const int e  = kg >> 9;
  const int kl = kg & 511;
  unsigned short* d = dst + (((size_t)b * 4 + e) * 512 + kl) * 1024 + t0 + tq;
#pragma unroll
  for (int s8 = 0; s8 < 2; s8++) {
    ushort8 rr;
#pragma unroll
    for (int j = 0; j < 8; j++) rr[j] = f32_bf16(tile[tq + s8 * 32 + j][kr]);
    *(ushort8*)(d + s8 * 32) = rr;   // quad lanes -> 64B contiguous
  }
}

// ---------------------------------------------------------------------------
// combine (B,T,E,C) fp32 -> bf16, plus row-sum S[b,t]
// ---------------------------------------------------------------------------
__global__ __launch_bounds__(256)
void cvt_combine_rowsum(const float* __restrict__ in,
                        unsigned short* __restrict__ out,
                        float* __restrict__ S) {
  const int row = blockIdx.x;
  const int u = threadIdx.x;
  const float4* p = (const float4*)(in + (size_t)row * 2048) + (size_t)u * 2;
  float4 a = p[0], b = p[1];
  ushort8 r;
  r[0] = f32_bf16(a.x); r[1] = f32_bf16(a.y);
  r[2] = f32_bf16(a.z); r[3] = f32_bf16(a.w);
  r[4] = f32_bf16(b.x); r[5] = f32_bf16(b.y);
  r[6] = f32_bf16(b.z); r[7] = f32_bf16(b.w);
  *((ushort8*)(out + (size_t)row * 2048) + u) = r;
  float s = (a.x + a.y + a.z + a.w) + (b.x + b.y + b.z + b.w);
  __shared__ float red[256];
  red[u] = s;
  __syncthreads();
#pragma unroll
  for (int st = 128; st > 0; st >>= 1) {
    if (u < st) red[u] += red[u + st];
    __syncthreads();
  }
  if (u == 0) S[row] = red[0];
}

// ---------------------------------------------------------------------------
// weight permute: w[e,o,i] -> W2[o, e*512+i] bf16
// ---------------------------------------------------------------------------
__global__ __launch_bounds__(256)
void permute_w(const float* __restrict__ weight, unsigned short* __restrict__ W2) {
  const int tid = blockIdx.x * 256 + threadIdx.x;
  const int i8 = tid & 63;
  const int e  = (tid >> 6) & 3;
  const int o  = tid >> 8;
  const float* s = weight + (size_t)e * 4194304 + (size_t)o * 512 + i8 * 8;
  float4 a = *(const float4*)s;
  float4 b = *(const float4*)(s + 4);
  ushort8 r;
  r[0] = f32_bf16(a.x); r[1] = f32_bf16(a.y);
  r[2] = f32_bf16(a.z); r[3] = f32_bf16(a.w);
  r[4] = f32_bf16(b.x); r[5] = f32_bf16(b.y);
  r[6] = f32_bf16(b.z); r[7] = f32_bf16(b.w);
  *(ushort8*)(W2 + (size_t)o * 2048 + e * 512 + i8 * 8) = r;
}

// ---------------------------------------------------------------------------
// gemm_bt (m97 structure, 128x128 tile): used for the two small GEMMs.
// ---------------------------------------------------------------------------
template <int MODE>
__global__ __launch_bounds__(256, 2)
void gemm_bt(const unsigned short* __restrict__ A,
             const unsigned short* __restrict__ Bm,
             void* __restrict__ Out, const float* __restrict__ bias,
             const float* __restrict__ S,
             int lda, int ldb, int ldo, int K, int Ediv,
             long sAb, long sAe, long sBb, long sBe, long sOb, long sOe) {
  __shared__ __align__(16) unsigned short As[128 * 32];
  __shared__ __align__(16) unsigned short Bs[128 * 32];
  const int u = threadIdx.x;
  const int z = blockIdx.z;
  const int zb = z / Ediv, ze = z % Ediv;
  const unsigned short* Ab = A  + zb * sAb + ze * sAe + (long)(blockIdx.y * 128) * lda;
  const unsigned short* Bb = Bm + zb * sBb + ze * sBe + (long)(blockIdx.x * 128) * ldb;

  const int srow = u >> 2;
  const int scol = (u & 3) * 8;
  const unsigned short* ga0 = Ab + (long)srow * lda + scol;
  const unsigned short* ga1 = ga0 + (long)64 * lda;
  const unsigned short* gb0 = Bb + (long)srow * ldb + scol;
  const unsigned short* gb1 = gb0 + (long)64 * ldb;

  const int w = u >> 6, lane = u & 63;
  unsigned short* la0 = As + w * 512;
  unsigned short* la1 = la0 + 2048;
  unsigned short* lb0 = Bs + w * 512;
  unsigned short* lb1 = lb0 + 2048;

  const int wm = (w & 1) * 64, wn = (w >> 1) * 64;
  const int fm = lane & 15, fk = (lane >> 4) * 8;
  const unsigned short* pA = As + (wm + fm) * 32 + fk;
  const unsigned short* pB = Bs + (wn + fm) * 32 + fk;

  f32x4 acc[4][4] = {};

  for (int kt = 0; kt < K; kt += 32) {
    __syncthreads();
    gl2lds16(ga0, la0);
    gl2lds16(ga1, la1);
    gl2lds16(gb0, lb0);
    gl2lds16(gb1, lb1);
    ga0 += 32; ga1 += 32; gb0 += 32; gb1 += 32;
    __syncthreads();
    bf16x8 af[4], bfv[4];
#pragma unroll
    for (int i = 0; i < 4; i++) {
      af[i]  = *(const bf16x8*)(pA + i * 16 * 32);
      bfv[i] = *(const bf16x8*)(pB + i * 16 * 32);
    }
#pragma unroll
    for (int i = 0; i < 4; i++)
#pragma unroll
      for (int j = 0; j < 4; j++)
        acc[i][j] = __builtin_amdgcn_mfma_f32_16x16x32_bf16(af[i], bfv[j],
                                                            acc[i][j], 0, 0, 0);
  }

  const long ob = zb * sOb + ze * sOe;
  const int em0 = blockIdx.y * 128 + wm + ((lane >> 4) << 2);
  const int en0 = blockIdx.x * 128 + wn + (lane & 15);
  float bcol[4];
  if (MODE == 1) {
#pragma unroll
    for (int j = 0; j < 4; j++) bcol[j] = bias[en0 + j * 16];
  }
#pragma unroll
  for (int i = 0; i < 4; i++)
#pragma unroll
    for (int r = 0; r < 4; r++) {
      const int m = em0 + i * 16 + r;
      const float sm = (MODE == 1) ? S[m] : 0.0f;
#pragma unroll
      for (int j = 0; j < 4; j++) {
        const long off = ob + (long)m * ldo + en0 + j * 16;
        if (MODE == 1)
          ((float*)Out)[off] = acc[i][j][r] + sm * bcol[j];
        else
          ((unsigned short*)Out)[off] = f32_bf16(acc[i][j][r]);
      }
    }
}

// ---------------------------------------------------------------------------
// gemm256: 256x256 tile, BK=64, 8 waves, 4-phase/K-tile (T1+T2+T3+T4+T5).
// D[m,n] = sum_k A[m,k]*B[n,k] + S[m]*bias[n].  M=4096 N=8192 K=2048.
//
// LDS: A buf0 [0,32K) | A buf1 [32K,64K) | B buf0 [64K,96K) | B buf1 [96K,128K)
// XOR swizzle byte ^= ((row&7)<<4); gl2lds writes linear, inverse swz on source.
//
// DEEP-PREFETCH schedule: all stages for K-tile kt+2 target the CURRENT buffer
// bb (since (kt+2)&1 == kt&1), placed at the phase where the slot goes dead:
//   p0: DSR a0(8)+bq nh0(4)      ; no stage          ; MFMA mh0 x nh0
//   p1: DSR a1(8)                ; STG A0(kt+2)->bb  ; MFMA mh1 x nh0
//   p2: DSR bq nh1(4)            ; STG A1(kt+2)->bb  ; MFMA mh0 x nh1
//   p3:                            STG B0,B1(kt+2)->bb; MFMA mh1 x nh1; vmcnt(8)
// Slot death: A0 read only at p0, A1 at p1, B at p0+p2; stages issue AFTER the
// closing barrier of the last-reading phase -> race-free.
// vmcnt(8) at p3 drains the PREVIOUS iteration's 8 loads (A,B of kt+1):
// B issue->wait distance = 4 phases (was 2), A = 5-6 phases. Never 0 in loop.
// Tail: kt+1/kt+2 clamped to 31 -> restages identical bytes (benign).
// ---------------------------------------------------------------------------
#define DSR(dst, addr) do { f32x4 _t_; \
    asm volatile("ds_read_b128 %0, %1" : "=v"(_t_) : "v"(addr)); \
    dst = __builtin_bit_cast(bf16x8, _t_); } while (0)

__global__ __launch_bounds__(512, 2)
void gemm256(const unsigned short* __restrict__ A,
             const unsigned short* __restrict__ Bm,
             float* __restrict__ Out,
             const float* __restrict__ bias,
             const float* __restrict__ S) {
  __shared__ __align__(16) unsigned short lds[65536];  // 128 KiB
  char* ldsg = (char*)lds;
  const unsigned ldsb =
      (unsigned)(unsigned long long)(__attribute__((address_space(3))) char*)(void*)lds;

  int wg = blockIdx.x;
  wg = (wg & 7) * 64 + (wg >> 3);      // bijective XCD swizzle (512 % 8 == 0)
  const int bx = wg & 31;              // N tile (8192/256)
  const int by = wg >> 5;              // M tile (4096/256)

  const int u = threadIdx.x;
  const int w = u >> 6, lane = u & 63;
  const unsigned w1024 = (unsigned)(w * 1024);
  const int wmw = (w >> 2) * 128;      // wave M offset in tile
  const int wnw = (w & 3) * 64;        // wave N offset in tile
  const int fm = lane & 15;

  // read-side swizzled column bases (byte ^= ((row&7)<<4); row&7 == fm&7)
  const unsigned hi16  = (unsigned)(((lane >> 4) & 3) * 16);
  const unsigned xorv  = (unsigned)((fm & 7) << 4);
  const unsigned colS0 = hi16 ^ xorv;
  const unsigned aR0 = (unsigned)((wmw + fm) * 128) + colS0;
  const unsigned aR1 = aR0 ^ 64u;                     // k-step 1 (+32 elems)
  const unsigned bR0 = 65536u + (unsigned)((wnw + fm) * 128) + colS0;
  const unsigned bR1 = bR0 ^ 64u;

  // stage-side: LDS dest linear (u*16B within half-tile); source pre-swizzled.
  const int srr = w * 8 + (lane >> 3);
  const unsigned swzS = (unsigned)((((lane & 7) ^ ((lane >> 3) & 7)) << 4));
  const char* gA = (const char*)(A  + (size_t)(by * 256) * 2048) + (size_t)srr * 4096 + swzS;
  const char* gB = (const char*)(Bm + (size_t)(bx * 256) * 2048) + (size_t)srr * 4096 + swzS;

  // one STG = one half-tile (128 rows x 128B): 2 x global_load_lds dwordx4 / thread
#define STG(gsrc, loff) do { \
    gl2lds16((gsrc), ldsg + (loff)); \
    gl2lds16((gsrc) + 262144, ldsg + (loff) + 8192); } while (0)

  // prologue: kt0 {A,B} -> buf0; kt1 {A,B} -> buf1; wait kt0 landed (8 left)
  STG(gA,                    0u + w1024);
  STG(gA + 524288,       16384u + w1024);
  STG(gB,                65536u + w1024);
  STG(gB + 524288,       81920u + w1024);
  STG(gA + 128,          32768u + w1024);
  STG(gA + 128 + 524288, 49152u + w1024);
  STG(gB + 128,          98304u + w1024);
  STG(gB + 128 + 524288, 114688u + w1024);
  asm volatile("s_waitcnt vmcnt(8)" ::: "memory");
  __builtin_amdgcn_s_barrier();

  f32x4 acc[8][4] = {};
  bf16x8 a0[4][2], a1[4][2], bq[2][2];

  for (int kt = 0; kt < 32; ++kt) {
    const unsigned bbO = (unsigned)((kt & 1) * 32768);
    const int ktn = (kt + 2 < 32) ? kt + 2 : 31;   // stage target K-tile
    const char* gAn = gA + ktn * 128;
    const char* gBn = gB + ktn * 128;

    // -------- phase 0: A[mh0] + B[nh0] reads; MFMA mh0 x nh0
#pragma unroll
    for (int i = 0; i < 4; ++i) {
      DSR(a0[i][0], ldsb + bbO + aR0 + (unsigned)(i * 2048));
      DSR(a0[i][1], ldsb + bbO + aR1 + (unsigned)(i * 2048));
    }
#pragma unroll
    for (int j = 0; j < 2; ++j) {
      DSR(bq[j][0], ldsb + bbO + bR0 + (unsigned)(j * 2048));
      DSR(bq[j][1], ldsb + bbO + bR1 + (unsigned)(j * 2048));
    }
    asm volatile("s_waitcnt lgkmcnt(8)" ::: "memory");  // early partial drain
    __builtin_amdgcn_s_barrier();
    asm volatile("s_waitcnt lgkmcnt(0)" ::: "memory");
    __builtin_amdgcn_sched_barrier(0);
    __builtin_amdgcn_s_setprio(1);
#pragma unroll
    for (int i = 0; i < 4; ++i)
#pragma unroll
      for (int j = 0; j < 2; ++j) {
        acc[i][j] = __builtin_amdgcn_mfma_f32_16x16x32_bf16(a0[i][0], bq[j][0], acc[i][j], 0, 0, 0);
        acc[i][j] = __builtin_amdgcn_mfma_f32_16x16x32_bf16(a0[i][1], bq[j][1], acc[i][j], 0, 0, 0);
      }
    __builtin_amdgcn_s_setprio(0);
    __builtin_amdgcn_s_barrier();

    // -------- phase 1: A[mh1] reads; stage A0(kt+2)->bb (A0 slot dead); MFMA mh1 x nh0
#pragma unroll
    for (int i = 0; i < 4; ++i) {
      DSR(a1[i][0], ldsb + bbO + aR0 + (unsigned)((4 + i) * 2048));
      DSR(a1[i][1], ldsb + bbO + aR1 + (unsigned)((4 + i) * 2048));
    }
    STG(gAn, bbO + w1024);
    __builtin_amdgcn_s_barrier();
    asm volatile("s_waitcnt lgkmcnt(0)" ::: "memory");
    __builtin_amdgcn_sched_barrier(0);
    __builtin_amdgcn_s_setprio(1);
#pragma unroll
    for (int i = 0; i < 4; ++i)
#pragma unroll
      for (int j = 0; j < 2; ++j) {
        acc[4 + i][j] = __builtin_amdgcn_mfma_f32_16x16x32_bf16(a1[i][0], bq[j][0], acc[4 + i][j], 0, 0, 0);
        acc[4 + i][j] = __builtin_amdgcn_mfma_f32_16x16x32_bf16(a1[i][1], bq[j][1], acc[4 + i][j], 0, 0, 0);
      }
    __builtin_amdgcn_s_setprio(0);
    __builtin_amdgcn_s_barrier();

    // -------- phase 2: B[nh1] reads (reuse bq); stage A1(kt+2)->bb; MFMA mh0 x nh1
#pragma unroll
    for (int j = 0; j < 2; ++j) {
      DSR(bq[j][0], ldsb + bbO + bR0 + (unsigned)((2 + j) * 2048));
      DSR(bq[j][1], ldsb + bbO + bR1 + (unsigned)((2 + j) * 2048));
    }
    STG(gAn + 524288, bbO + 16384u + w1024);
    __builtin_amdgcn_s_barrier();
    asm volatile("s_waitcnt lgkmcnt(0)" ::: "memory");
    __builtin_amdgcn_sched_barrier(0);
    __builtin_amdgcn_s_setprio(1);
#pragma unroll
    for (int i = 0; i < 4; ++i)
#pragma unroll
      for (int j = 0; j < 2; ++j) {
        acc[i][2 + j] = __builtin_amdgcn_mfma_f32_16x16x32_bf16(a0[i][0], bq[j][0], acc[i][2 + j], 0, 0, 0);
        acc[i][2 + j] = __builtin_amdgcn_mfma_f32_16x16x32_bf16(a0[i][1], bq[j][1], acc[i][2 + j], 0, 0, 0);
      }
    __builtin_amdgcn_s_setprio(0);
    __builtin_amdgcn_s_barrier();

    // -------- phase 3: stage B0,B1(kt+2)->bb (B slots dead); MFMA mh1 x nh1; vmcnt(8)
    STG(gBn,          65536u + bbO + w1024);
    STG(gBn + 524288, 81920u + bbO + w1024);
    __builtin_amdgcn_s_barrier();
    __builtin_amdgcn_s_setprio(1);
#pragma unroll
    for (int i = 0; i < 4; ++i)
#pragma unroll
      for (int j = 0; j < 2; ++j) {
        acc[4 + i][2 + j] = __builtin_amdgcn_mfma_f32_16x16x32_bf16(a1[i][0], bq[j][0], acc[4 + i][2 + j], 0, 0, 0);
        acc[4 + i][2 + j] = __builtin_amdgcn_mfma_f32_16x16x32_bf16(a1[i][1], bq[j][1], acc[4 + i][2 + j], 0, 0, 0);
      }
    __builtin_amdgcn_s_setprio(0);
    asm volatile("s_waitcnt vmcnt(8)" ::: "memory");  // drain kt+1's A,B only
    __builtin_amdgcn_sched_barrier(0);
    __builtin_amdgcn_s_barrier();
  }
#undef STG
  asm volatile("s_waitcnt vmcnt(0)" ::: "memory");  // no in-flight LDS writes at exit

  // epilogue: C/D layout col=lane&15, row=(lane>>4)*4+reg  [m89/m91]
  const int m0 = by * 256 + wmw + ((lane >> 4) << 2);
  const int n0 = bx * 256 + wnw + (lane & 15);
  float bc[4];
#pragma unroll
  for (int j = 0; j < 4; ++j) bc[j] = bias[n0 + j * 16];
#pragma unroll
  for (int i = 0; i < 8; ++i)
#pragma unroll
    for (int r = 0; r < 4; ++r) {
      const int m = m0 + i * 16 + r;
      const float sm = S[m];
#pragma unroll
      for (int j = 0; j < 4; ++j)
        Out[(size_t)m * 8192 + n0 + j * 16] = acc[i][j][r] + sm * bc[j];
    }
}

// ---------------------------------------------------------------------------
// launch
// ---------------------------------------------------------------------------
extern "C" void kernel_launch(void* const* d_in, const int* in_sizes, int n_in,
                              void* d_out, int out_size, void* d_ws,
                              size_t ws_size, hipStream_t stream) {
  (void)in_sizes; (void)n_in; (void)out_size; (void)ws_size;
  const float* x       = (const float*)d_in[0];  // (B,T,IN)
  const float* combine = (const float*)d_in[1];  // (B,T,E,C)
  const float* mask    = (const float*)d_in[2];  // (B,T,E,C)
  const float* weight  = (const float*)d_in[3];  // (OUT,IN)
  const float* bias    = (const float*)d_in[4];  // (OUT,)
  float* out = (float*)d_out;                    // (B,T,OUT) fp32

  // workspace layout (~105 MB)
  char* ws = (char*)d_ws;
  unsigned short* W2      = (unsigned short*)ws;                    // 32 MB
  unsigned short* comb_bf = (unsigned short*)(ws + 33554432);       // 16 MB
  float*          S       = (float*)(ws + 50331648);                // 16 KB
  unsigned short* xT      = (unsigned short*)(ws + 51380224);       // 16 MB
  unsigned short* maskT   = (unsigned short*)(ws + 68157440);       // 16 MB
  unsigned short* xdT     = (unsigned short*)(ws + 84934656);       //  8 MB
  unsigned short* zbuf    = (unsigned short*)(ws + 93323264);       // 16 MB

  // 0) layout/dtype prep
  transpose_cvt2<<<dim3(32, 16, 8), 256, 0, stream>>>(x, mask, xT, maskT);
  cvt_combine_rowsum<<<4096, 256, 0, stream>>>(combine, comb_bf, S);
  permute_w<<<8192, 256, 0, stream>>>(weight, W2);                  // W2[o,(e,i)]

  // 1) xdT[b,e,i,c] = sum_t xT[b,e,i,t] * maskT[b,e,c,t]
  gemm_bt<0><<<dim3(4, 4, 16), 256, 0, stream>>>(
      xT, maskT, (void*)xdT, nullptr, nullptr, 1024, 1024, 512, 1024,
      4, 2097152L, 524288L, 2097152L, 524288L, 1048576L, 262144L);

  // 2) z[b,t,(e,i)] = sum_c comb_bf[b,t,e,c] * xdT[b,e,i,c]
  gemm_bt<0><<<dim3(4, 8, 16), 256, 0, stream>>>(
      comb_bf, xdT, (void*)zbuf, nullptr, nullptr, 2048, 512, 2048, 512,
      4, 2097152L, 512L, 1048576L, 262144L, 2097152L, 512L);

  // 3) out[m,o] = sum_{(e,i)} z[m,(e,i)] * W2[o,(e,i)] + S[m]*bias[o]
  //    M=4096 N=8192 K=2048 — 256^2 deep-prefetch kernel
  gemm256<<<dim3(512), 512, 0, stream>>>(zbuf, W2, out, bias, S);
}

// Round 3
// 415.334 us; speedup vs baseline: 1.0330x; 1.0330x over previous
//
#include <hip/hip_runtime.h>

// Problem constants (from reference setup_inputs)
#define B_   4
#define T_   1024
#define E_   4
#define C_   512
#define IN_  2048
#define OUT_ 8192
#define EI_  512   // expert in-features = IN_/E_

typedef float f32x4 __attribute__((ext_vector_type(4)));
typedef __bf16 bf16x8 __attribute__((ext_vector_type(8)));
typedef unsigned short ushort8 __attribute__((ext_vector_type(8)));

__device__ __forceinline__ unsigned short f32_bf16(float f) {
  unsigned int u = __float_as_uint(f);
  u += 0x7FFFu + ((u >> 16) & 1u);   // round-to-nearest-even (finite inputs)
  return (unsigned short)(u >> 16);
}

__device__ __forceinline__ void gl2lds16(const void* g, void* l) {
  __builtin_amdgcn_global_load_lds(
      (const __attribute__((address_space(1))) void*)g,
      (__attribute__((address_space(3))) void*)l, 16, 0, 0);
}

// ---------------------------------------------------------------------------
// Fused prep: one launch, three independent jobs selected by blockIdx range.
//  [0,4096)    : transpose-convert x/mask (B,T,2048) fp32 -> (B,4,512,T) bf16
//  [4096,8192) : combine fp32->bf16 + row-sum S
//  [8192,16384): weight permute w[e,o,i] -> W2[o, e*512+i] bf16
// ---------------------------------------------------------------------------
__global__ __launch_bounds__(256)
void prep(const float* __restrict__ xsrc, const float* __restrict__ msrc,
          const float* __restrict__ combine, const float* __restrict__ weight,
          unsigned short* __restrict__ xdst, unsigned short* __restrict__ mdst,
          unsigned short* __restrict__ comb_bf, float* __restrict__ S,
          unsigned short* __restrict__ W2) {
  const int bid = blockIdx.x;
  const int u = threadIdx.x;
  if (bid < 4096) {
    // ---- transpose_cvt2 body ----
    __shared__ float tile[64][65];
    const int z = bid >> 9;             // 0..7
    const int which = z >> 2;
    const int b = z & 3;
    const int rem = bid & 511;
    const int t0 = (rem >> 5) * 64;
    const int k0 = (rem & 31) * 64;
    const float* src = which ? msrc : xsrc;
    unsigned short* dst = which ? mdst : xdst;
    const int lrow = u >> 4;
    const int lcol = (u & 15) * 4;
    const float* s = src + (size_t)b * (T_ * 2048) + (size_t)t0 * 2048 + k0;
#pragma unroll
    for (int r = 0; r < 4; r++) {
      float4 v = *(const float4*)(s + (size_t)(lrow + 16 * r) * 2048 + lcol);
      tile[lrow + 16 * r][lcol]     = v.x;
      tile[lrow + 16 * r][lcol + 1] = v.y;
      tile[lrow + 16 * r][lcol + 2] = v.z;
      tile[lrow + 16 * r][lcol + 3] = v.w;
    }
    __syncthreads();
    const int kr = u >> 2;
    const int tq = (u & 3) * 8;
    const int kg = k0 + kr;
    const int e  = kg >> 9;
    const int kl = kg & 511;
    unsigned short* d = dst + (((size_t)b * 4 + e) * 512 + kl) * 1024 + t0 + tq;
#pragma unroll
    for (int s8 = 0; s8 < 2; s8++) {
      ushort8 rr;
#pragma unroll
      for (int j = 0; j < 8; j++) rr[j] = f32_bf16(tile[tq + s8 * 32 + j][kr]);
      *(ushort8*)(d + s8 * 32) = rr;
    }
  } else if (bid < 8192) {
    // ---- cvt_combine_rowsum body ----
    __shared__ float red[256];
    const int row = bid - 4096;
    const float4* p = (const float4*)(combine + (size_t)row * 2048) + (size_t)u * 2;
    float4 a = p[0], b = p[1];
    ushort8 r;
    r[0] = f32_bf16(a.x); r[1] = f32_bf16(a.y);
    r[2] = f32_bf16(a.z); r[3] = f32_bf16(a.w);
    r[4] = f32_bf16(b.x); r[5] = f32_bf16(b.y);
    r[6] = f32_bf16(b.z); r[7] = f32_bf16(b.w);
    *((ushort8*)(comb_bf + (size_t)row * 2048) + u) = r;
    float s = (a.x + a.y + a.z + a.w) + (b.x + b.y + b.z + b.w);
    red[u] = s;
    __syncthreads();
#pragma unroll
    for (int st = 128; st > 0; st >>= 1) {
      if (u < st) red[u] += red[u + st];
      __syncthreads();
    }
    if (u == 0) S[row] = red[0];
  } else {
    // ---- permute_w body ----
    const int tid = (bid - 8192) * 256 + u;
    const int i8 = tid & 63;
    const int e  = (tid >> 6) & 3;
    const int o  = tid >> 8;
    const float* s = weight + (size_t)e * 4194304 + (size_t)o * 512 + i8 * 8;
    float4 a = *(const float4*)s;
    float4 b = *(const float4*)(s + 4);
    ushort8 r;
    r[0] = f32_bf16(a.x); r[1] = f32_bf16(a.y);
    r[2] = f32_bf16(a.z); r[3] = f32_bf16(a.w);
    r[4] = f32_bf16(b.x); r[5] = f32_bf16(b.y);
    r[6] = f32_bf16(b.z); r[7] = f32_bf16(b.w);
    *(ushort8*)(W2 + (size_t)o * 2048 + e * 512 + i8 * 8) = r;
  }
}

// ---------------------------------------------------------------------------
// gemm_bt: 128x128 tile, now DOUBLE-BUFFERED (T3-minimal): STAGE(next) issued
// BEFORE compute(cur); __syncthreads' implicit vmcnt(0)+lgkmcnt(0) at the end
// of the iteration is the only drain. Hides the global->LDS round trip under
// the current tile's MFMA (critical at 1 block/CU where there is no TLP).
// ---------------------------------------------------------------------------
template <int MODE>
__global__ __launch_bounds__(256, 2)
void gemm_bt(const unsigned short* __restrict__ A,
             const unsigned short* __restrict__ Bm,
             void* __restrict__ Out, const float* __restrict__ bias,
             const float* __restrict__ S,
             int lda, int ldb, int ldo, int K, int Ediv,
             long sAb, long sAe, long sBb, long sBe, long sOb, long sOe) {
  __shared__ __align__(16) unsigned short As[2][4096];  // 2 x 8 KB
  __shared__ __align__(16) unsigned short Bs[2][4096];
  const int u = threadIdx.x;
  const int z = blockIdx.z;
  const int zb = z / Ediv, ze = z % Ediv;
  const unsigned short* Ab = A  + zb * sAb + ze * sAe + (long)(blockIdx.y * 128) * lda;
  const unsigned short* Bb = Bm + zb * sBb + ze * sBe + (long)(blockIdx.x * 128) * ldb;

  const int srow = u >> 2;
  const int scol = (u & 3) * 8;
  const unsigned short* ga0 = Ab + (long)srow * lda + scol;
  const unsigned short* ga1 = ga0 + (long)64 * lda;
  const unsigned short* gb0 = Bb + (long)srow * ldb + scol;
  const unsigned short* gb1 = gb0 + (long)64 * ldb;

  const int w = u >> 6, lane = u & 63;
  const int wq = w * 512;

  const int wm = (w & 1) * 64, wn = (w >> 1) * 64;
  const int fm = lane & 15, fk = (lane >> 4) * 8;

  f32x4 acc[4][4] = {};

  // prologue: stage tile 0 into buffer 0, wait for it
  gl2lds16(ga0, As[0] + wq);
  gl2lds16(ga1, As[0] + wq + 2048);
  gl2lds16(gb0, Bs[0] + wq);
  gl2lds16(gb1, Bs[0] + wq + 2048);
  ga0 += 32; ga1 += 32; gb0 += 32; gb1 += 32;
  __syncthreads();   // implicit vmcnt(0): buf0 landed

  const int nt = K / 32;
  for (int t = 0; t < nt; ++t) {
    const int cur = t & 1;
    if (t + 1 < nt) {                      // issue next-tile stage FIRST
      const int nx = cur ^ 1;
      gl2lds16(ga0, As[nx] + wq);
      gl2lds16(ga1, As[nx] + wq + 2048);
      gl2lds16(gb0, Bs[nx] + wq);
      gl2lds16(gb1, Bs[nx] + wq + 2048);
      ga0 += 32; ga1 += 32; gb0 += 32; gb1 += 32;
    }
    const unsigned short* pA = As[cur] + (wm + fm) * 32 + fk;
    const unsigned short* pB = Bs[cur] + (wn + fm) * 32 + fk;
    bf16x8 af[4], bfv[4];
#pragma unroll
    for (int i = 0; i < 4; i++) {
      af[i]  = *(const bf16x8*)(pA + i * 16 * 32);
      bfv[i] = *(const bf16x8*)(pB + i * 16 * 32);
    }
#pragma unroll
    for (int i = 0; i < 4; i++)
#pragma unroll
      for (int j = 0; j < 4; j++)
        acc[i][j] = __builtin_amdgcn_mfma_f32_16x16x32_bf16(af[i], bfv[j],
                                                            acc[i][j], 0, 0, 0);
    __syncthreads();   // drains vmcnt(0): next buf ready; cur reads done
  }

  const long ob = zb * sOb + ze * sOe;
  const int em0 = blockIdx.y * 128 + wm + ((lane >> 4) << 2);
  const int en0 = blockIdx.x * 128 + wn + (lane & 15);
  float bcol[4];
  if (MODE == 1) {
#pragma unroll
    for (int j = 0; j < 4; j++) bcol[j] = bias[en0 + j * 16];
  }
#pragma unroll
  for (int i = 0; i < 4; i++)
#pragma unroll
    for (int r = 0; r < 4; r++) {
      const int m = em0 + i * 16 + r;
      const float sm = (MODE == 1) ? S[m] : 0.0f;
#pragma unroll
      for (int j = 0; j < 4; j++) {
        const long off = ob + (long)m * ldo + en0 + j * 16;
        if (MODE == 1)
          ((float*)Out)[off] = acc[i][j][r] + sm * bcol[j];
        else
          ((unsigned short*)Out)[off] = f32_bf16(acc[i][j][r]);
      }
    }
}

// ---------------------------------------------------------------------------
// gemm256: 256x256 tile, BK=64, 8 waves, 4-phase/K-tile — ROUND-0 schedule
// (best measured: 136 µs / MfmaUtil 42%). D = A·B^T + S[m]*bias[n].
//
// LDS: A buf0 [0,32K) | A buf1 [32K,64K) | B buf0 [64K,96K) | B buf1 [96K,128K)
// XOR swizzle byte ^= ((row&7)<<4); gl2lds writes linear, inverse swz on src.
//
// Stage placement (liveness-verified; per-wave reads span BOTH half-tiles of
// A and B in p0/p1 (A) and p0/p2 (B), so A slots of bb die only after p1 and
// B slots of bb only after p2):
//   p0: DSR a0(8)+bq nh0(4); STG B0(kt+1)->nb ; MFMA mh0 x nh0
//   p1: DSR a1(8)          ; STG B1(kt+1)->nb ; MFMA mh1 x nh0
//   p2: DSR bq nh1(4)      ; STG A0(kt+2)->bb ; MFMA mh0 x nh1
//   p3:                      STG A1(kt+2)->bb ; MFMA mh1 x nh1; vmcnt(4)
// vmcnt(4) is TIGHT: leaves exactly the p2/p3 A(kt+2) stages in flight and
// drains B(kt+1) + A(kt+1) (staged last iter) before they are read. Never 0
// in the loop; final vmcnt(0) after the loop drains the clamped tail stages.
// ---------------------------------------------------------------------------
#define DSR(dst, addr) do { f32x4 _t_; \
    asm volatile("ds_read_b128 %0, %1" : "=v"(_t_) : "v"(addr)); \
    dst = __builtin_bit_cast(bf16x8, _t_); } while (0)

__global__ __launch_bounds__(512, 2)
void gemm256(const unsigned short* __restrict__ A,
             const unsigned short* __restrict__ Bm,
             float* __restrict__ Out,
             const float* __restrict__ bias,
             const float* __restrict__ S) {
  __shared__ __align__(16) unsigned short lds[65536];  // 128 KiB
  char* ldsg = (char*)lds;
  const unsigned ldsb =
      (unsigned)(unsigned long long)(__attribute__((address_space(3))) char*)(void*)lds;

  int wg = blockIdx.x;
  wg = (wg & 7) * 64 + (wg >> 3);      // bijective XCD swizzle (512 % 8 == 0)
  const int bx = wg & 31;              // N tile (8192/256)
  const int by = wg >> 5;              // M tile (4096/256)

  const int u = threadIdx.x;
  const int w = u >> 6, lane = u & 63;
  const unsigned w1024 = (unsigned)(w * 1024);
  const int wmw = (w >> 2) * 128;      // wave M offset in tile
  const int wnw = (w & 3) * 64;        // wave N offset in tile
  const int fm = lane & 15;

  // read-side swizzled column bases (byte ^= ((row&7)<<4); row&7 == fm&7)
  const unsigned hi16  = (unsigned)(((lane >> 4) & 3) * 16);
  const unsigned xorv  = (unsigned)((fm & 7) << 4);
  const unsigned colS0 = hi16 ^ xorv;
  const unsigned aR0 = (unsigned)((wmw + fm) * 128) + colS0;
  const unsigned aR1 = aR0 ^ 64u;                     // k-step 1 (+32 elems)
  const unsigned bR0 = 65536u + (unsigned)((wnw + fm) * 128) + colS0;
  const unsigned bR1 = bR0 ^ 64u;

  // stage-side: LDS dest linear (u*16B within half-tile); source pre-swizzled.
  const int srr = w * 8 + (lane >> 3);
  const unsigned swzS = (unsigned)((((lane & 7) ^ ((lane >> 3) & 7)) << 4));
  const char* gA = (const char*)(A  + (size_t)(by * 256) * 2048) + (size_t)srr * 4096 + swzS;
  const char* gB = (const char*)(Bm + (size_t)(bx * 256) * 2048) + (size_t)srr * 4096 + swzS;

  // one STG = one half-tile (128 rows x 128B): 2 x global_load_lds dwordx4 / thread
#define STG(gsrc, loff) do { \
    gl2lds16((gsrc), ldsg + (loff)); \
    gl2lds16((gsrc) + 262144, ldsg + (loff) + 8192); } while (0)

  // prologue: kt0 {A0,A1,B0,B1} -> buf0; kt1 {A0,A1} -> buf1; wait kt0 landed
  STG(gA,                    0u + w1024);
  STG(gA + 524288,       16384u + w1024);
  STG(gB,                65536u + w1024);
  STG(gB + 524288,       81920u + w1024);
  STG(gA + 128,          32768u + w1024);
  STG(gA + 128 + 524288, 49152u + w1024);
  asm volatile("s_waitcnt vmcnt(4)" ::: "memory");
  __builtin_amdgcn_s_barrier();

  f32x4 acc[8][4] = {};
  bf16x8 a0[4][2], a1[4][2], bq[2][2];

  for (int kt = 0; kt < 32; ++kt) {
    const unsigned bbO = (unsigned)((kt & 1) * 32768);
    const unsigned nbR = bbO ^ 32768u;
    const int ktB = (kt + 1 < 32) ? kt + 1 : 31;
    const int ktA = (kt + 2 < 32) ? kt + 2 : 31;
    const char* gBn = gB + ktB * 128;
    const char* gAn = gA + ktA * 128;

    // -------- phase 0: A[mh0] + B[nh0] reads; stage B0(kt+1); MFMA mh0 x nh0
#pragma unroll
    for (int i = 0; i < 4; ++i) {
      DSR(a0[i][0], ldsb + bbO + aR0 + (unsigned)(i * 2048));
      DSR(a0[i][1], ldsb + bbO + aR1 + (unsigned)(i * 2048));
    }
#pragma unroll
    for (int j = 0; j < 2; ++j) {
      DSR(bq[j][0], ldsb + bbO + bR0 + (unsigned)(j * 2048));
      DSR(bq[j][1], ldsb + bbO + bR1 + (unsigned)(j * 2048));
    }
    STG(gBn, 65536u + nbR + w1024);
    __builtin_amdgcn_s_barrier();
    asm volatile("s_waitcnt lgkmcnt(0)" ::: "memory");
    __builtin_amdgcn_sched_barrier(0);
    __builtin_amdgcn_s_setprio(1);
#pragma unroll
    for (int i = 0; i < 4; ++i)
#pragma unroll
      for (int j = 0; j < 2; ++j) {
        acc[i][j] = __builtin_amdgcn_mfma_f32_16x16x32_bf16(a0[i][0], bq[j][0], acc[i][j], 0, 0, 0);
        acc[i][j] = __builtin_amdgcn_mfma_f32_16x16x32_bf16(a0[i][1], bq[j][1], acc[i][j], 0, 0, 0);
      }
    __builtin_amdgcn_s_setprio(0);
    __builtin_amdgcn_s_barrier();

    // -------- phase 1: A[mh1] reads; stage B1(kt+1); MFMA mh1 x nh0
#pragma unroll
    for (int i = 0; i < 4; ++i) {
      DSR(a1[i][0], ldsb + bbO + aR0 + (unsigned)((4 + i) * 2048));
      DSR(a1[i][1], ldsb + bbO + aR1 + (unsigned)((4 + i) * 2048));
    }
    STG(gBn + 524288, 81920u + nbR + w1024);
    __builtin_amdgcn_s_barrier();
    asm volatile("s_waitcnt lgkmcnt(0)" ::: "memory");
    __builtin_amdgcn_sched_barrier(0);
    __builtin_amdgcn_s_setprio(1);
#pragma unroll
    for (int i = 0; i < 4; ++i)
#pragma unroll
      for (int j = 0; j < 2; ++j) {
        acc[4 + i][j] = __builtin_amdgcn_mfma_f32_16x16x32_bf16(a1[i][0], bq[j][0], acc[4 + i][j], 0, 0, 0);
        acc[4 + i][j] = __builtin_amdgcn_mfma_f32_16x16x32_bf16(a1[i][1], bq[j][1], acc[4 + i][j], 0, 0, 0);
      }
    __builtin_amdgcn_s_setprio(0);
    __builtin_amdgcn_s_barrier();

    // -------- phase 2: B[nh1] reads (reuse bq); stage A0(kt+2); MFMA mh0 x nh1
#pragma unroll
    for (int j = 0; j < 2; ++j) {
      DSR(bq[j][0], ldsb + bbO + bR0 + (unsigned)((2 + j) * 2048));
      DSR(bq[j][1], ldsb + bbO + bR1 + (unsigned)((2 + j) * 2048));
    }
    STG(gAn, bbO + w1024);
    __builtin_amdgcn_s_barrier();
    asm volatile("s_waitcnt lgkmcnt(0)" ::: "memory");
    __builtin_amdgcn_sched_barrier(0);
    __builtin_amdgcn_s_setprio(1);
#pragma unroll
    for (int i = 0; i < 4; ++i)
#pragma unroll
      for (int j = 0; j < 2; ++j) {
        acc[i][2 + j] = __builtin_amdgcn_mfma_f32_16x16x32_bf16(a0[i][0], bq[j][0], acc[i][2 + j], 0, 0, 0);
        acc[i][2 + j] = __builtin_amdgcn_mfma_f32_16x16x32_bf16(a0[i][1], bq[j][1], acc[i][2 + j], 0, 0, 0);
      }
    __builtin_amdgcn_s_setprio(0);
    __builtin_amdgcn_s_barrier();

    // -------- phase 3: stage A1(kt+2); MFMA mh1 x nh1; counted vmcnt(4)
    STG(gAn + 524288, bbO + 16384u + w1024);
    __builtin_amdgcn_s_barrier();
    __builtin_amdgcn_s_setprio(1);
#pragma unroll
    for (int i = 0; i < 4; ++i)
#pragma unroll
      for (int j = 0; j < 2; ++j) {
        acc[4 + i][2 + j] = __builtin_amdgcn_mfma_f32_16x16x32_bf16(a1[i][0], bq[j][0], acc[4 + i][2 + j], 0, 0, 0);
        acc[4 + i][2 + j] = __builtin_amdgcn_mfma_f32_16x16x32_bf16(a1[i][1], bq[j][1], acc[4 + i][2 + j], 0, 0, 0);
      }
    __builtin_amdgcn_s_setprio(0);
    asm volatile("s_waitcnt vmcnt(4)" ::: "memory");
    __builtin_amdgcn_sched_barrier(0);
    __builtin_amdgcn_s_barrier();
  }
#undef STG
  asm volatile("s_waitcnt vmcnt(0)" ::: "memory");  // drain tail stages before exit

  // epilogue: C/D layout col=lane&15, row=(lane>>4)*4+reg  [m89/m91]
  const int m0 = by * 256 + wmw + ((lane >> 4) << 2);
  const int n0 = bx * 256 + wnw + (lane & 15);
  float bc[4];
#pragma unroll
  for (int j = 0; j < 4; ++j) bc[j] = bias[n0 + j * 16];
#pragma unroll
  for (int i = 0; i < 8; ++i)
#pragma unroll
    for (int r = 0; r < 4; ++r) {
      const int m = m0 + i * 16 + r;
      const float sm = S[m];
#pragma unroll
      for (int j = 0; j < 4; ++j)
        Out[(size_t)m * 8192 + n0 + j * 16] = acc[i][j][r] + sm * bc[j];
    }
}

// ---------------------------------------------------------------------------
// launch
// ---------------------------------------------------------------------------
extern "C" void kernel_launch(void* const* d_in, const int* in_sizes, int n_in,
                              void* d_out, int out_size, void* d_ws,
                              size_t ws_size, hipStream_t stream) {
  (void)in_sizes; (void)n_in; (void)out_size; (void)ws_size;
  const float* x       = (const float*)d_in[0];  // (B,T,IN)
  const float* combine = (const float*)d_in[1];  // (B,T,E,C)
  const float* mask    = (const float*)d_in[2];  // (B,T,E,C)
  const float* weight  = (const float*)d_in[3];  // (OUT,IN)
  const float* bias    = (const float*)d_in[4];  // (OUT,)
  float* out = (float*)d_out;                    // (B,T,OUT) fp32

  // workspace layout (~105 MB)
  char* ws = (char*)d_ws;
  unsigned short* W2      = (unsigned short*)ws;                    // 32 MB
  unsigned short* comb_bf = (unsigned short*)(ws + 33554432);       // 16 MB
  float*          S       = (float*)(ws + 50331648);                // 16 KB
  unsigned short* xT      = (unsigned short*)(ws + 51380224);       // 16 MB
  unsigned short* maskT   = (unsigned short*)(ws + 68157440);       // 16 MB
  unsigned short* xdT     = (unsigned short*)(ws + 84934656);       //  8 MB
  unsigned short* zbuf    = (unsigned short*)(ws + 93323264);       // 16 MB

  // 0) all layout/dtype prep in ONE launch
  prep<<<16384, 256, 0, stream>>>(x, mask, combine, weight, xT, maskT,
                                  comb_bf, S, W2);

  // 1) xdT[b,e,i,c] = sum_t xT[b,e,i,t] * maskT[b,e,c,t]
  gemm_bt<0><<<dim3(4, 4, 16), 256, 0, stream>>>(
      xT, maskT, (void*)xdT, nullptr, nullptr, 1024, 1024, 512, 1024,
      4, 2097152L, 524288L, 2097152L, 524288L, 1048576L, 262144L);

  // 2) z[b,t,(e,i)] = sum_c comb_bf[b,t,e,c] * xdT[b,e,i,c]
  gemm_bt<0><<<dim3(4, 8, 16), 256, 0, stream>>>(
      comb_bf, xdT, (void*)zbuf, nullptr, nullptr, 2048, 512, 2048, 512,
      4, 2097152L, 512L, 1048576L, 262144L, 2097152L, 512L);

  // 3) out[m,o] = sum_{(e,i)} z[m,(e,i)] * W2[o,(e,i)] + S[m]*bias[o]
  //    M=4096 N=8192 K=2048 — 256^2 round-0 schedule
  gemm256<<<dim3(512), 512, 0, stream>>>(zbuf, W2, out, bias, S);
}

// Round 5
// 414.886 us; speedup vs baseline: 1.0341x; 1.0011x over previous
//
#include <hip/hip_runtime.h>

// Problem constants (from reference setup_inputs)
#define B_   4
#define T_   1024
#define E_   4
#define C_   512
#define IN_  2048
#define OUT_ 8192
#define EI_  512   // expert in-features = IN_/E_

typedef float f32x4 __attribute__((ext_vector_type(4)));
typedef __bf16 bf16x8 __attribute__((ext_vector_type(8)));
typedef unsigned short ushort8 __attribute__((ext_vector_type(8)));

__device__ __forceinline__ unsigned short f32_bf16(float f) {
  unsigned int u = __float_as_uint(f);
  u += 0x7FFFu + ((u >> 16) & 1u);   // round-to-nearest-even (finite inputs)
  return (unsigned short)(u >> 16);
}

__device__ __forceinline__ void gl2lds16(const void* g, void* l) {
  __builtin_amdgcn_global_load_lds(
      (const __attribute__((address_space(1))) void*)g,
      (__attribute__((address_space(3))) void*)l, 16, 0, 0);
}

#define DSR(dst, addr) do { f32x4 _t_; \
    asm volatile("ds_read_b128 %0, %1" : "=v"(_t_) : "v"(addr)); \
    dst = __builtin_bit_cast(bf16x8, _t_); } while (0)

// ---------------------------------------------------------------------------
// Fused prep: one launch, three independent jobs selected by blockIdx range.
//  [0,4096)    : transpose-convert x/mask (B,T,2048) fp32 -> (B,4,512,T) bf16
//  [4096,8192) : combine fp32->bf16 + row-sum S
//  [8192,16384): weight permute w[e,o,i] -> W2[o, e*512+i] bf16
// ---------------------------------------------------------------------------
__global__ __launch_bounds__(256)
void prep(const float* __restrict__ xsrc, const float* __restrict__ msrc,
          const float* __restrict__ combine, const float* __restrict__ weight,
          unsigned short* __restrict__ xdst, unsigned short* __restrict__ mdst,
          unsigned short* __restrict__ comb_bf, float* __restrict__ S,
          unsigned short* __restrict__ W2) {
  const int bid = blockIdx.x;
  const int u = threadIdx.x;
  if (bid < 4096) {
    // ---- transpose_cvt body ----
    __shared__ float tile[64][65];
    const int z = bid >> 9;             // 0..7
    const int which = z >> 2;
    const int b = z & 3;
    const int rem = bid & 511;
    const int t0 = (rem >> 5) * 64;
    const int k0 = (rem & 31) * 64;
    const float* src = which ? msrc : xsrc;
    unsigned short* dst = which ? mdst : xdst;
    const int lrow = u >> 4;
    const int lcol = (u & 15) * 4;
    const float* s = src + (size_t)b * (T_ * 2048) + (size_t)t0 * 2048 + k0;
#pragma unroll
    for (int r = 0; r < 4; r++) {
      float4 v = *(const float4*)(s + (size_t)(lrow + 16 * r) * 2048 + lcol);
      tile[lrow + 16 * r][lcol]     = v.x;
      tile[lrow + 16 * r][lcol + 1] = v.y;
      tile[lrow + 16 * r][lcol + 2] = v.z;
      tile[lrow + 16 * r][lcol + 3] = v.w;
    }
    __syncthreads();
    const int kr = u >> 2;
    const int tq = (u & 3) * 8;
    const int kg = k0 + kr;
    const int e  = kg >> 9;
    const int kl = kg & 511;
    unsigned short* d = dst + (((size_t)b * 4 + e) * 512 + kl) * 1024 + t0 + tq;
#pragma unroll
    for (int s8 = 0; s8 < 2; s8++) {
      ushort8 rr;
#pragma unroll
      for (int j = 0; j < 8; j++) rr[j] = f32_bf16(tile[tq + s8 * 32 + j][kr]);
      *(ushort8*)(d + s8 * 32) = rr;
    }
  } else if (bid < 8192) {
    // ---- cvt_combine_rowsum body ----
    __shared__ float red[256];
    const int row = bid - 4096;
    const float4* p = (const float4*)(combine + (size_t)row * 2048) + (size_t)u * 2;
    float4 a = p[0], b = p[1];
    ushort8 r;
    r[0] = f32_bf16(a.x); r[1] = f32_bf16(a.y);
    r[2] = f32_bf16(a.z); r[3] = f32_bf16(a.w);
    r[4] = f32_bf16(b.x); r[5] = f32_bf16(b.y);
    r[6] = f32_bf16(b.z); r[7] = f32_bf16(b.w);
    *((ushort8*)(comb_bf + (size_t)row * 2048) + u) = r;
    float s = (a.x + a.y + a.z + a.w) + (b.x + b.y + b.z + b.w);
    red[u] = s;
    __syncthreads();
#pragma unroll
    for (int st = 128; st > 0; st >>= 1) {
      if (u < st) red[u] += red[u + st];
      __syncthreads();
    }
    if (u == 0) S[row] = red[0];
  } else {
    // ---- permute_w body ----
    const int tid = (bid - 8192) * 256 + u;
    const int i8 = tid & 63;
    const int e  = (tid >> 6) & 3;
    const int o  = tid >> 8;
    const float* s = weight + (size_t)e * 4194304 + (size_t)o * 512 + i8 * 8;
    float4 a = *(const float4*)s;
    float4 b = *(const float4*)(s + 4);
    ushort8 r;
    r[0] = f32_bf16(a.x); r[1] = f32_bf16(a.y);
    r[2] = f32_bf16(a.z); r[3] = f32_bf16(a.w);
    r[4] = f32_bf16(b.x); r[5] = f32_bf16(b.y);
    r[6] = f32_bf16(b.z); r[7] = f32_bf16(b.w);
    *(ushort8*)(W2 + (size_t)o * 2048 + e * 512 + i8 * 8) = r;
  }
}

// ---------------------------------------------------------------------------
// gemm_bt: 128x128 tile, TRIPLE-BUFFERED with raw s_barrier + counted vmcnt
// (the __syncthreads dbuf was a false pipeline: implicit vmcnt(0) at the
// barrier drained the just-issued stage, exposing ~full HBM latency/K-step
// at 1 block/CU). Here: stage t+2 -> buf[(t+2)%3] each iter; vmcnt(4) at the
// bottom drains only t+1's batch -> prefetch distance ~2 iterations.
// Liveness: buf[(t+2)%3]==buf[(t-1)%3], last read in iter t-1, sealed by that
// iter's closing barrier. Exactly 4 loads/iter (tail clamps SOURCE only), so
// the vmcnt counts are exact.
// ---------------------------------------------------------------------------
template <int MODE>
__global__ __launch_bounds__(256, 2)
void gemm_bt(const unsigned short* __restrict__ A,
             const unsigned short* __restrict__ Bm,
             void* __restrict__ Out, const float* __restrict__ bias,
             const float* __restrict__ S,
             int lda, int ldb, int ldo, int K, int Ediv,
             long sAb, long sAe, long sBb, long sBe, long sOb, long sOe) {
  // A bufs: [0, 24576) = 3 x 8KB ; B bufs: [24576, 49152)
  __shared__ __align__(16) char ldsRaw[49152];
  char* ldsg = ldsRaw;
  const unsigned ldsb =
      (unsigned)(unsigned long long)(__attribute__((address_space(3))) char*)(void*)ldsRaw;

  const int u = threadIdx.x;
  const int z = blockIdx.z;
  const int zb = z / Ediv, ze = z % Ediv;
  const unsigned short* Ab = A  + zb * sAb + ze * sAe + (long)(blockIdx.y * 128) * lda;
  const unsigned short* Bb = Bm + zb * sBb + ze * sBe + (long)(blockIdx.x * 128) * ldb;

  const int srow = u >> 2;            // staging row 0..63
  const int scol = (u & 3) * 8;
  const unsigned short* gA = Ab + (long)srow * lda + scol;
  const unsigned short* gB = Bb + (long)srow * ldb + scol;
  const long a64 = (long)64 * lda, b64 = (long)64 * ldb;

  const int w = u >> 6, lane = u & 63;
  const unsigned w1024 = (unsigned)(w * 1024);

  const int wm = (w & 1) * 64, wn = (w >> 1) * 64;
  const int fm = lane & 15, fk = (lane >> 4) * 8;
  const unsigned aF = (unsigned)((wm + fm) * 64 + fk * 2);           // byte off in A buf
  const unsigned bF = 24576u + (unsigned)((wn + fm) * 64 + fk * 2);  // byte off (B region)

  f32x4 acc[4][4] = {};

  const int nt = K / 32;   // >= 16 for all uses
#define STGBT(buf, kk) do { \
    const unsigned short* a_ = gA + (kk) * 32; \
    const unsigned short* b_ = gB + (kk) * 32; \
    gl2lds16(a_,       ldsg + (buf) * 8192 + w1024); \
    gl2lds16(a_ + a64, ldsg + (buf) * 8192 + 4096 + w1024); \
    gl2lds16(b_,       ldsg + 24576 + (buf) * 8192 + w1024); \
    gl2lds16(b_ + b64, ldsg + 24576 + (buf) * 8192 + 4096 + w1024); } while (0)

  // prologue: tiles 0,1 -> bufs 0,1; wait tile 0 landed (leave tile 1's 4)
  STGBT(0, 0);
  STGBT(1, 1);
  asm volatile("s_waitcnt vmcnt(4)" ::: "memory");
  __builtin_amdgcn_s_barrier();

  int cur = 0, pre = 2;
  for (int t = 0; t < nt; ++t) {
    bf16x8 af[4], bfv[4];
    const unsigned cb = (unsigned)(cur * 8192);
#pragma unroll
    for (int i = 0; i < 4; i++) {
      DSR(af[i],  ldsb + cb + aF + (unsigned)(i * 1024));
      DSR(bfv[i], ldsb + cb + bF + (unsigned)(i * 1024));
    }
    const int kk = (t + 2 < nt) ? t + 2 : nt - 1;   // clamp source only
    STGBT(pre, kk);
    asm volatile("s_waitcnt lgkmcnt(0)" ::: "memory");
    __builtin_amdgcn_sched_barrier(0);
    __builtin_amdgcn_s_setprio(1);
#pragma unroll
    for (int i = 0; i < 4; i++)
#pragma unroll
      for (int j = 0; j < 4; j++)
        acc[i][j] = __builtin_amdgcn_mfma_f32_16x16x32_bf16(af[i], bfv[j],
                                                            acc[i][j], 0, 0, 0);
    __builtin_amdgcn_s_setprio(0);
    asm volatile("s_waitcnt vmcnt(4)" ::: "memory");  // drain t+1's stage
    __builtin_amdgcn_sched_barrier(0);
    __builtin_amdgcn_s_barrier();
    cur = (cur == 2) ? 0 : cur + 1;
    pre = (pre == 2) ? 0 : pre + 1;
  }
#undef STGBT
  asm volatile("s_waitcnt vmcnt(0)" ::: "memory");  // drain tail stages

  const long ob = zb * sOb + ze * sOe;
  const int em0 = blockIdx.y * 128 + wm + ((lane >> 4) << 2);
  const int en0 = blockIdx.x * 128 + wn + (lane & 15);
  float bcol[4];
  if (MODE == 1) {
#pragma unroll
    for (int j = 0; j < 4; j++) bcol[j] = bias[en0 + j * 16];
  }
#pragma unroll
  for (int i = 0; i < 4; i++)
#pragma unroll
    for (int r = 0; r < 4; r++) {
      const int m = em0 + i * 16 + r;
      const float sm = (MODE == 1) ? S[m] : 0.0f;
#pragma unroll
      for (int j = 0; j < 4; j++) {
        const long off = ob + (long)m * ldo + en0 + j * 16;
        if (MODE == 1)
          ((float*)Out)[off] = acc[i][j][r] + sm * bcol[j];
        else
          ((unsigned short*)Out)[off] = f32_bf16(acc[i][j][r]);
      }
    }
}

// ---------------------------------------------------------------------------
// gemm256: 256x256 tile, BK=64, 8 waves, 4-phase/K-tile — round-0 schedule
// (best measured). D = A·B^T + S[m]*bias[n].  M=4096 N=8192 K=2048.
// Round-3 change under test: NONTEMPORAL epilogue stores. The 128 MB fp32
// output was write-allocating through L2/L3 and evicting the 48 MB A/B
// working set (FETCH_SIZE 270 MB vs 48 MB of inputs -> 5.6x re-fetch).
//
// LDS: A buf0 [0,32K) | A buf1 [32K,64K) | B buf0 [64K,96K) | B buf1 [96K,128K)
// XOR swizzle byte ^= ((row&7)<<4); gl2lds writes linear, inverse swz on src.
//   p0: DSR a0(8)+bq nh0(4); STG B0(kt+1)->nb ; MFMA mh0 x nh0
//   p1: DSR a1(8)          ; STG B1(kt+1)->nb ; MFMA mh1 x nh0
//   p2: DSR bq nh1(4)      ; STG A0(kt+2)->bb ; MFMA mh0 x nh1
//   p3:                      STG A1(kt+2)->bb ; MFMA mh1 x nh1; vmcnt(4)
// ---------------------------------------------------------------------------
__global__ __launch_bounds__(512, 2)
void gemm256(const unsigned short* __restrict__ A,
             const unsigned short* __restrict__ Bm,
             float* __restrict__ Out,
             const float* __restrict__ bias,
             const float* __restrict__ S) {
  __shared__ __align__(16) unsigned short lds[65536];  // 128 KiB
  char* ldsg = (char*)lds;
  const unsigned ldsb =
      (unsigned)(unsigned long long)(__attribute__((address_space(3))) char*)(void*)lds;

  int wg = blockIdx.x;
  wg = (wg & 7) * 64 + (wg >> 3);      // bijective XCD swizzle (512 % 8 == 0)
  const int bx = wg & 31;              // N tile (8192/256)
  const int by = wg >> 5;              // M tile (4096/256)

  const int u = threadIdx.x;
  const int w = u >> 6, lane = u & 63;
  const unsigned w1024 = (unsigned)(w * 1024);
  const int wmw = (w >> 2) * 128;      // wave M offset in tile
  const int wnw = (w & 3) * 64;        // wave N offset in tile
  const int fm = lane & 15;

  // read-side swizzled column bases (byte ^= ((row&7)<<4); row&7 == fm&7)
  const unsigned hi16  = (unsigned)(((lane >> 4) & 3) * 16);
  const unsigned xorv  = (unsigned)((fm & 7) << 4);
  const unsigned colS0 = hi16 ^ xorv;
  const unsigned aR0 = (unsigned)((wmw + fm) * 128) + colS0;
  const unsigned aR1 = aR0 ^ 64u;                     // k-step 1 (+32 elems)
  const unsigned bR0 = 65536u + (unsigned)((wnw + fm) * 128) + colS0;
  const unsigned bR1 = bR0 ^ 64u;

  // stage-side: LDS dest linear (u*16B within half-tile); source pre-swizzled.
  const int srr = w * 8 + (lane >> 3);
  const unsigned swzS = (unsigned)((((lane & 7) ^ ((lane >> 3) & 7)) << 4));
  const char* gA = (const char*)(A  + (size_t)(by * 256) * 2048) + (size_t)srr * 4096 + swzS;
  const char* gB = (const char*)(Bm + (size_t)(bx * 256) * 2048) + (size_t)srr * 4096 + swzS;

  // one STG = one half-tile (128 rows x 128B): 2 x global_load_lds dwordx4 / thread
#define STG(gsrc, loff) do { \
    gl2lds16((gsrc), ldsg + (loff)); \
    gl2lds16((gsrc) + 262144, ldsg + (loff) + 8192); } while (0)

  // prologue: kt0 {A0,A1,B0,B1} -> buf0; kt1 {A0,A1} -> buf1; wait kt0 landed
  STG(gA,                    0u + w1024);
  STG(gA + 524288,       16384u + w1024);
  STG(gB,                65536u + w1024);
  STG(gB + 524288,       81920u + w1024);
  STG(gA + 128,          32768u + w1024);
  STG(gA + 128 + 524288, 49152u + w1024);
  asm volatile("s_waitcnt vmcnt(4)" ::: "memory");
  __builtin_amdgcn_s_barrier();

  f32x4 acc[8][4] = {};
  bf16x8 a0[4][2], a1[4][2], bq[2][2];

  for (int kt = 0; kt < 32; ++kt) {
    const unsigned bbO = (unsigned)((kt & 1) * 32768);
    const unsigned nbR = bbO ^ 32768u;
    const int ktB = (kt + 1 < 32) ? kt + 1 : 31;
    const int ktA = (kt + 2 < 32) ? kt + 2 : 31;
    const char* gBn = gB + ktB * 128;
    const char* gAn = gA + ktA * 128;

    // -------- phase 0: A[mh0] + B[nh0] reads; stage B0(kt+1); MFMA mh0 x nh0
#pragma unroll
    for (int i = 0; i < 4; ++i) {
      DSR(a0[i][0], ldsb + bbO + aR0 + (unsigned)(i * 2048));
      DSR(a0[i][1], ldsb + bbO + aR1 + (unsigned)(i * 2048));
    }
#pragma unroll
    for (int j = 0; j < 2; ++j) {
      DSR(bq[j][0], ldsb + bbO + bR0 + (unsigned)(j * 2048));
      DSR(bq[j][1], ldsb + bbO + bR1 + (unsigned)(j * 2048));
    }
    STG(gBn, 65536u + nbR + w1024);
    __builtin_amdgcn_s_barrier();
    asm volatile("s_waitcnt lgkmcnt(0)" ::: "memory");
    __builtin_amdgcn_sched_barrier(0);
    __builtin_amdgcn_s_setprio(1);
#pragma unroll
    for (int i = 0; i < 4; ++i)
#pragma unroll
      for (int j = 0; j < 2; ++j) {
        acc[i][j] = __builtin_amdgcn_mfma_f32_16x16x32_bf16(a0[i][0], bq[j][0], acc[i][j], 0, 0, 0);
        acc[i][j] = __builtin_amdgcn_mfma_f32_16x16x32_bf16(a0[i][1], bq[j][1], acc[i][j], 0, 0, 0);
      }
    __builtin_amdgcn_s_setprio(0);
    __builtin_amdgcn_s_barrier();

    // -------- phase 1: A[mh1] reads; stage B1(kt+1); MFMA mh1 x nh0
#pragma unroll
    for (int i = 0; i < 4; ++i) {
      DSR(a1[i][0], ldsb + bbO + aR0 + (unsigned)((4 + i) * 2048));
      DSR(a1[i][1], ldsb + bbO + aR1 + (unsigned)((4 + i) * 2048));
    }
    STG(gBn + 524288, 81920u + nbR + w1024);
    __builtin_amdgcn_s_barrier();
    asm volatile("s_waitcnt lgkmcnt(0)" ::: "memory");
    __builtin_amdgcn_sched_barrier(0);
    __builtin_amdgcn_s_setprio(1);
#pragma unroll
    for (int i = 0; i < 4; ++i)
#pragma unroll
      for (int j = 0; j < 2; ++j) {
        acc[4 + i][j] = __builtin_amdgcn_mfma_f32_16x16x32_bf16(a1[i][0], bq[j][0], acc[4 + i][j], 0, 0, 0);
        acc[4 + i][j] = __builtin_amdgcn_mfma_f32_16x16x32_bf16(a1[i][1], bq[j][1], acc[4 + i][j], 0, 0, 0);
      }
    __builtin_amdgcn_s_setprio(0);
    __builtin_amdgcn_s_barrier();

    // -------- phase 2: B[nh1] reads (reuse bq); stage A0(kt+2); MFMA mh0 x nh1
#pragma unroll
    for (int j = 0; j < 2; ++j) {
      DSR(bq[j][0], ldsb + bbO + bR0 + (unsigned)((2 + j) * 2048));
      DSR(bq[j][1], ldsb + bbO + bR1 + (unsigned)((2 + j) * 2048));
    }
    STG(gAn, bbO + w1024);
    __builtin_amdgcn_s_barrier();
    asm volatile("s_waitcnt lgkmcnt(0)" ::: "memory");
    __builtin_amdgcn_sched_barrier(0);
    __builtin_amdgcn_s_setprio(1);
#pragma unroll
    for (int i = 0; i < 4; ++i)
#pragma unroll
      for (int j = 0; j < 2; ++j) {
        acc[i][2 + j] = __builtin_amdgcn_mfma_f32_16x16x32_bf16(a0[i][0], bq[j][0], acc[i][2 + j], 0, 0, 0);
        acc[i][2 + j] = __builtin_amdgcn_mfma_f32_16x16x32_bf16(a0[i][1], bq[j][1], acc[i][2 + j], 0, 0, 0);
      }
    __builtin_amdgcn_s_setprio(0);
    __builtin_amdgcn_s_barrier();

    // -------- phase 3: stage A1(kt+2); MFMA mh1 x nh1; counted vmcnt(4)
    STG(gAn + 524288, bbO + 16384u + w1024);
    __builtin_amdgcn_s_barrier();
    __builtin_amdgcn_s_setprio(1);
#pragma unroll
    for (int i = 0; i < 4; ++i)
#pragma unroll
      for (int j = 0; j < 2; ++j) {
        acc[4 + i][2 + j] = __builtin_amdgcn_mfma_f32_16x16x32_bf16(a1[i][0], bq[j][0], acc[4 + i][2 + j], 0, 0, 0);
        acc[4 + i][2 + j] = __builtin_amdgcn_mfma_f32_16x16x32_bf16(a1[i][1], bq[j][1], acc[4 + i][2 + j], 0, 0, 0);
      }
    __builtin_amdgcn_s_setprio(0);
    asm volatile("s_waitcnt vmcnt(4)" ::: "memory");
    __builtin_amdgcn_sched_barrier(0);
    __builtin_amdgcn_s_barrier();
  }
#undef STG
  asm volatile("s_waitcnt vmcnt(0)" ::: "memory");  // drain tail stages before exit

  // epilogue: C/D layout col=lane&15, row=(lane>>4)*4+reg  [m89/m91]
  // Nontemporal stores: output is never re-read on-GPU; keep L2/L3 for A/B.
  const int m0 = by * 256 + wmw + ((lane >> 4) << 2);
  const int n0 = bx * 256 + wnw + (lane & 15);
  float bc[4];
#pragma unroll
  for (int j = 0; j < 4; ++j) bc[j] = bias[n0 + j * 16];
#pragma unroll
  for (int i = 0; i < 8; ++i)
#pragma unroll
    for (int r = 0; r < 4; ++r) {
      const int m = m0 + i * 16 + r;
      const float sm = S[m];
#pragma unroll
      for (int j = 0; j < 4; ++j)
        __builtin_nontemporal_store(acc[i][j][r] + sm * bc[j],
                                    &Out[(size_t)m * 8192 + n0 + j * 16]);
    }
}

// ---------------------------------------------------------------------------
// launch
// ---------------------------------------------------------------------------
extern "C" void kernel_launch(void* const* d_in, const int* in_sizes, int n_in,
                              void* d_out, int out_size, void* d_ws,
                              size_t ws_size, hipStream_t stream) {
  (void)in_sizes; (void)n_in; (void)out_size; (void)ws_size;
  const float* x       = (const float*)d_in[0];  // (B,T,IN)
  const float* combine = (const float*)d_in[1];  // (B,T,E,C)
  const float* mask    = (const float*)d_in[2];  // (B,T,E,C)
  const float* weight  = (const float*)d_in[3];  // (OUT,IN)
  const float* bias    = (const float*)d_in[4];  // (OUT,)
  float* out = (float*)d_out;                    // (B,T,OUT) fp32

  // workspace layout (~105 MB)
  char* ws = (char*)d_ws;
  unsigned short* W2      = (unsigned short*)ws;                    // 32 MB
  unsigned short* comb_bf = (unsigned short*)(ws + 33554432);       // 16 MB
  float*          S       = (float*)(ws + 50331648);                // 16 KB
  unsigned short* xT      = (unsigned short*)(ws + 51380224);       // 16 MB
  unsigned short* maskT   = (unsigned short*)(ws + 68157440);       // 16 MB
  unsigned short* xdT     = (unsigned short*)(ws + 84934656);       //  8 MB
  unsigned short* zbuf    = (unsigned short*)(ws + 93323264);       // 16 MB

  // 0) all layout/dtype prep in ONE launch
  prep<<<16384, 256, 0, stream>>>(x, mask, combine, weight, xT, maskT,
                                  comb_bf, S, W2);

  // 1) xdT[b,e,i,c] = sum_t xT[b,e,i,t] * maskT[b,e,c,t]
  gemm_bt<0><<<dim3(4, 4, 16), 256, 0, stream>>>(
      xT, maskT, (void*)xdT, nullptr, nullptr, 1024, 1024, 512, 1024,
      4, 2097152L, 524288L, 2097152L, 524288L, 1048576L, 262144L);

  // 2) z[b,t,(e,i)] = sum_c comb_bf[b,t,e,c] * xdT[b,e,i,c]
  gemm_bt<0><<<dim3(4, 8, 16), 256, 0, stream>>>(
      comb_bf, xdT, (void*)zbuf, nullptr, nullptr, 2048, 512, 2048, 512,
      4, 2097152L, 512L, 1048576L, 262144L, 2097152L, 512L);

  // 3) out[m,o] = sum_{(e,i)} z[m,(e,i)] * W2[o,(e,i)] + S[m]*bias[o]
  //    M=4096 N=8192 K=2048 — 256^2 round-0 schedule + nt stores
  gemm256<<<dim3(512), 512, 0, stream>>>(zbuf, W2, out, bias, S);
}

// Round 6
// 407.139 us; speedup vs baseline: 1.0538x; 1.0190x over previous
//
#include <hip/hip_runtime.h>

// Problem constants (from reference setup_inputs)
#define B_   4
#define T_   1024
#define E_   4
#define C_   512
#define IN_  2048
#define OUT_ 8192
#define EI_  512   // expert in-features = IN_/E_

typedef float f32x4 __attribute__((ext_vector_type(4)));
typedef __bf16 bf16x8 __attribute__((ext_vector_type(8)));
typedef unsigned short ushort8 __attribute__((ext_vector_type(8)));

__device__ __forceinline__ unsigned short f32_bf16(float f) {
  unsigned int u = __float_as_uint(f);
  u += 0x7FFFu + ((u >> 16) & 1u);   // round-to-nearest-even (finite inputs)
  return (unsigned short)(u >> 16);
}

__device__ __forceinline__ void gl2lds16(const void* g, void* l) {
  __builtin_amdgcn_global_load_lds(
      (const __attribute__((address_space(1))) void*)g,
      (__attribute__((address_space(3))) void*)l, 16, 0, 0);
}

#define DSR(dst, addr) do { f32x4 _t_; \
    asm volatile("ds_read_b128 %0, %1" : "=v"(_t_) : "v"(addr)); \
    dst = __builtin_bit_cast(bf16x8, _t_); } while (0)

// ---------------------------------------------------------------------------
// Fused prep: one launch, three independent jobs selected by blockIdx range.
//  [0,4096)    : transpose-convert x/mask (B,T,2048) fp32 -> (B,4,512,T) bf16
//  [4096,8192) : combine fp32->bf16 + row-sum S
//  [8192,16384): weight permute w[e,o,i] -> W2[o, e*512+i] bf16
// ---------------------------------------------------------------------------
__global__ __launch_bounds__(256)
void prep(const float* __restrict__ xsrc, const float* __restrict__ msrc,
          const float* __restrict__ combine, const float* __restrict__ weight,
          unsigned short* __restrict__ xdst, unsigned short* __restrict__ mdst,
          unsigned short* __restrict__ comb_bf, float* __restrict__ S,
          unsigned short* __restrict__ W2) {
  const int bid = blockIdx.x;
  const int u = threadIdx.x;
  if (bid < 4096) {
    // ---- transpose_cvt body ----
    __shared__ float tile[64][65];
    const int z = bid >> 9;             // 0..7
    const int which = z >> 2;
    const int b = z & 3;
    const int rem = bid & 511;
    const int t0 = (rem >> 5) * 64;
    const int k0 = (rem & 31) * 64;
    const float* src = which ? msrc : xsrc;
    unsigned short* dst = which ? mdst : xdst;
    const int lrow = u >> 4;
    const int lcol = (u & 15) * 4;
    const float* s = src + (size_t)b * (T_ * 2048) + (size_t)t0 * 2048 + k0;
#pragma unroll
    for (int r = 0; r < 4; r++) {
      float4 v = *(const float4*)(s + (size_t)(lrow + 16 * r) * 2048 + lcol);
      tile[lrow + 16 * r][lcol]     = v.x;
      tile[lrow + 16 * r][lcol + 1] = v.y;
      tile[lrow + 16 * r][lcol + 2] = v.z;
      tile[lrow + 16 * r][lcol + 3] = v.w;
    }
    __syncthreads();
    const int kr = u >> 2;
    const int tq = (u & 3) * 8;
    const int kg = k0 + kr;
    const int e  = kg >> 9;
    const int kl = kg & 511;
    unsigned short* d = dst + (((size_t)b * 4 + e) * 512 + kl) * 1024 + t0 + tq;
#pragma unroll
    for (int s8 = 0; s8 < 2; s8++) {
      ushort8 rr;
#pragma unroll
      for (int j = 0; j < 8; j++) rr[j] = f32_bf16(tile[tq + s8 * 32 + j][kr]);
      *(ushort8*)(d + s8 * 32) = rr;
    }
  } else if (bid < 8192) {
    // ---- cvt_combine_rowsum body ----
    __shared__ float red[256];
    const int row = bid - 4096;
    const float4* p = (const float4*)(combine + (size_t)row * 2048) + (size_t)u * 2;
    float4 a = p[0], b = p[1];
    ushort8 r;
    r[0] = f32_bf16(a.x); r[1] = f32_bf16(a.y);
    r[2] = f32_bf16(a.z); r[3] = f32_bf16(a.w);
    r[4] = f32_bf16(b.x); r[5] = f32_bf16(b.y);
    r[6] = f32_bf16(b.z); r[7] = f32_bf16(b.w);
    *((ushort8*)(comb_bf + (size_t)row * 2048) + u) = r;
    float s = (a.x + a.y + a.z + a.w) + (b.x + b.y + b.z + b.w);
    red[u] = s;
    __syncthreads();
#pragma unroll
    for (int st = 128; st > 0; st >>= 1) {
      if (u < st) red[u] += red[u + st];
      __syncthreads();
    }
    if (u == 0) S[row] = red[0];
  } else {
    // ---- permute_w body ----
    const int tid = (bid - 8192) * 256 + u;
    const int i8 = tid & 63;
    const int e  = (tid >> 6) & 3;
    const int o  = tid >> 8;
    const float* s = weight + (size_t)e * 4194304 + (size_t)o * 512 + i8 * 8;
    float4 a = *(const float4*)s;
    float4 b = *(const float4*)(s + 4);
    ushort8 r;
    r[0] = f32_bf16(a.x); r[1] = f32_bf16(a.y);
    r[2] = f32_bf16(a.z); r[3] = f32_bf16(a.w);
    r[4] = f32_bf16(b.x); r[5] = f32_bf16(b.y);
    r[6] = f32_bf16(b.z); r[7] = f32_bf16(b.w);
    *(ushort8*)(W2 + (size_t)o * 2048 + e * 512 + i8 * 8) = r;
  }
}

// ---------------------------------------------------------------------------
// gemm_bt: 128x128 tile, BK=32, now 512 THREADS / 8 WAVES (2 waves/SIMD —
// previous 256-thread version had 1 wave/SIMD: zero intra-SIMD overlap, all
// LDS/stage/barrier latency fully exposed). Per-wave output 64x32 (2M x 4N
// wave grid). Triple-buffered, counted vmcnt(2): stage t+2 -> buf[(t+2)%3]
// each iter (2 gl2lds/thread covers the whole 8KB+8KB tile pair), drain t+1's
// pair at the bottom -> ~2-iteration prefetch distance.
// LDS row-major [128][32] bf16: 64B rows -> 2 rows span all 32 banks,
// fragment reads are bank-balanced without swizzle (m97-family layout).
// ---------------------------------------------------------------------------
template <int MODE>
__global__ __launch_bounds__(512, 2)
void gemm_bt(const unsigned short* __restrict__ A,
             const unsigned short* __restrict__ Bm,
             void* __restrict__ Out, const float* __restrict__ bias,
             const float* __restrict__ S,
             int lda, int ldb, int ldo, int K, int Ediv,
             long sAb, long sAe, long sBb, long sBe, long sOb, long sOe) {
  // A bufs: [0, 24576) = 3 x 8KB ; B bufs: [24576, 49152)
  __shared__ __align__(16) char ldsRaw[49152];
  char* ldsg = ldsRaw;
  const unsigned ldsb =
      (unsigned)(unsigned long long)(__attribute__((address_space(3))) char*)(void*)ldsRaw;

  const int u = threadIdx.x;
  const int z = blockIdx.z;
  const int zb = z / Ediv, ze = z % Ediv;
  const unsigned short* Ab = A  + zb * sAb + ze * sAe + (long)(blockIdx.y * 128) * lda;
  const unsigned short* Bb = Bm + zb * sBb + ze * sBe + (long)(blockIdx.x * 128) * ldb;

  // staging: 4 lanes per 64B row, 512 threads cover 128 rows x 32 k
  const unsigned short* gA = Ab + (long)(u >> 2) * lda + (u & 3) * 8;
  const unsigned short* gB = Bb + (long)(u >> 2) * ldb + (u & 3) * 8;

  const int w = u >> 6, lane = u & 63;
  const int wm = (w & 1) * 64, wn = (w >> 1) * 32;   // 2M x 4N wave grid
  const int fm = lane & 15, fk = (lane >> 4) * 8;
  const unsigned aF = (unsigned)((wm + fm) * 64 + fk * 2);           // byte off in A buf
  const unsigned bF = 24576u + (unsigned)((wn + fm) * 64 + fk * 2);  // byte off (B region)
  const unsigned u16 = (unsigned)(u * 16);

  f32x4 acc[4][2] = {};

  const int nt = K / 32;   // >= 16 for all uses
#define STGBT(buf, kk) do { \
    gl2lds16(gA + (kk) * 32, ldsg + (buf) * 8192 + u16); \
    gl2lds16(gB + (kk) * 32, ldsg + 24576 + (buf) * 8192 + u16); } while (0)

  // prologue: tiles 0,1 -> bufs 0,1; wait tile 0 landed (leave tile 1's 2)
  STGBT(0, 0);
  STGBT(1, 1);
  asm volatile("s_waitcnt vmcnt(2)" ::: "memory");
  __builtin_amdgcn_s_barrier();

  int cur = 0, pre = 2;
  for (int t = 0; t < nt; ++t) {
    bf16x8 af[4], bfv[2];
    const unsigned cb = (unsigned)(cur * 8192);
#pragma unroll
    for (int i = 0; i < 4; i++) DSR(af[i], ldsb + cb + aF + (unsigned)(i * 1024));
#pragma unroll
    for (int j = 0; j < 2; j++) DSR(bfv[j], ldsb + cb + bF + (unsigned)(j * 1024));
    const int kk = (t + 2 < nt) ? t + 2 : nt - 1;   // clamp source only
    STGBT(pre, kk);
    asm volatile("s_waitcnt lgkmcnt(0)" ::: "memory");
    __builtin_amdgcn_sched_barrier(0);
    __builtin_amdgcn_s_setprio(1);
#pragma unroll
    for (int i = 0; i < 4; i++)
#pragma unroll
      for (int j = 0; j < 2; j++)
        acc[i][j] = __builtin_amdgcn_mfma_f32_16x16x32_bf16(af[i], bfv[j],
                                                            acc[i][j], 0, 0, 0);
    __builtin_amdgcn_s_setprio(0);
    asm volatile("s_waitcnt vmcnt(2)" ::: "memory");  // drain t+1's stage
    __builtin_amdgcn_sched_barrier(0);
    __builtin_amdgcn_s_barrier();
    cur = (cur == 2) ? 0 : cur + 1;
    pre = (pre == 2) ? 0 : pre + 1;
  }
#undef STGBT
  asm volatile("s_waitcnt vmcnt(0)" ::: "memory");  // drain tail stages

  const long ob = zb * sOb + ze * sOe;
  const int em0 = blockIdx.y * 128 + wm + ((lane >> 4) << 2);
  const int en0 = blockIdx.x * 128 + wn + fm;
  float bcol[2];
  if (MODE == 1) {
#pragma unroll
    for (int j = 0; j < 2; j++) bcol[j] = bias[en0 + j * 16];
  }
#pragma unroll
  for (int i = 0; i < 4; i++)
#pragma unroll
    for (int r = 0; r < 4; r++) {
      const int m = em0 + i * 16 + r;
      const float sm = (MODE == 1) ? S[m] : 0.0f;
#pragma unroll
      for (int j = 0; j < 2; j++) {
        const long off = ob + (long)m * ldo + en0 + j * 16;
        if (MODE == 1)
          ((float*)Out)[off] = acc[i][j][r] + sm * bcol[j];
        else
          ((unsigned short*)Out)[off] = f32_bf16(acc[i][j][r]);
      }
    }
}

// ---------------------------------------------------------------------------
// gemm256: 256x256 tile, BK=64, 8 waves, 4-phase/K-tile — round-0 schedule
// (best measured: 136 µs). D = A·B^T + S[m]*bias[n].  M=4096 N=8192 K=2048.
// Nontemporal stores REVERTED (measured: WRITE_SIZE 131->161 MB regression,
// FETCH_SIZE unchanged -> write-allocate theory falsified).
//
// LDS: A buf0 [0,32K) | A buf1 [32K,64K) | B buf0 [64K,96K) | B buf1 [96K,128K)
// XOR swizzle byte ^= ((row&7)<<4); gl2lds writes linear, inverse swz on src.
//   p0: DSR a0(8)+bq nh0(4); STG B0(kt+1)->nb ; MFMA mh0 x nh0
//   p1: DSR a1(8)          ; STG B1(kt+1)->nb ; MFMA mh1 x nh0
//   p2: DSR bq nh1(4)      ; STG A0(kt+2)->bb ; MFMA mh0 x nh1
//   p3:                      STG A1(kt+2)->bb ; MFMA mh1 x nh1; vmcnt(4)
// ---------------------------------------------------------------------------
__global__ __launch_bounds__(512, 2)
void gemm256(const unsigned short* __restrict__ A,
             const unsigned short* __restrict__ Bm,
             float* __restrict__ Out,
             const float* __restrict__ bias,
             const float* __restrict__ S) {
  __shared__ __align__(16) unsigned short lds[65536];  // 128 KiB
  char* ldsg = (char*)lds;
  const unsigned ldsb =
      (unsigned)(unsigned long long)(__attribute__((address_space(3))) char*)(void*)lds;

  int wg = blockIdx.x;
  wg = (wg & 7) * 64 + (wg >> 3);      // bijective XCD swizzle (512 % 8 == 0)
  const int bx = wg & 31;              // N tile (8192/256)
  const int by = wg >> 5;              // M tile (4096/256)

  const int u = threadIdx.x;
  const int w = u >> 6, lane = u & 63;
  const unsigned w1024 = (unsigned)(w * 1024);
  const int wmw = (w >> 2) * 128;      // wave M offset in tile
  const int wnw = (w & 3) * 64;        // wave N offset in tile
  const int fm = lane & 15;

  // read-side swizzled column bases (byte ^= ((row&7)<<4); row&7 == fm&7)
  const unsigned hi16  = (unsigned)(((lane >> 4) & 3) * 16);
  const unsigned xorv  = (unsigned)((fm & 7) << 4);
  const unsigned colS0 = hi16 ^ xorv;
  const unsigned aR0 = (unsigned)((wmw + fm) * 128) + colS0;
  const unsigned aR1 = aR0 ^ 64u;                     // k-step 1 (+32 elems)
  const unsigned bR0 = 65536u + (unsigned)((wnw + fm) * 128) + colS0;
  const unsigned bR1 = bR0 ^ 64u;

  // stage-side: LDS dest linear (u*16B within half-tile); source pre-swizzled.
  const int srr = w * 8 + (lane >> 3);
  const unsigned swzS = (unsigned)((((lane & 7) ^ ((lane >> 3) & 7)) << 4));
  const char* gA = (const char*)(A  + (size_t)(by * 256) * 2048) + (size_t)srr * 4096 + swzS;
  const char* gB = (const char*)(Bm + (size_t)(bx * 256) * 2048) + (size_t)srr * 4096 + swzS;

  // one STG = one half-tile (128 rows x 128B): 2 x global_load_lds dwordx4 / thread
#define STG(gsrc, loff) do { \
    gl2lds16((gsrc), ldsg + (loff)); \
    gl2lds16((gsrc) + 262144, ldsg + (loff) + 8192); } while (0)

  // prologue: kt0 {A0,A1,B0,B1} -> buf0; kt1 {A0,A1} -> buf1; wait kt0 landed
  STG(gA,                    0u + w1024);
  STG(gA + 524288,       16384u + w1024);
  STG(gB,                65536u + w1024);
  STG(gB + 524288,       81920u + w1024);
  STG(gA + 128,          32768u + w1024);
  STG(gA + 128 + 524288, 49152u + w1024);
  asm volatile("s_waitcnt vmcnt(4)" ::: "memory");
  __builtin_amdgcn_s_barrier();

  f32x4 acc[8][4] = {};
  bf16x8 a0[4][2], a1[4][2], bq[2][2];

  for (int kt = 0; kt < 32; ++kt) {
    const unsigned bbO = (unsigned)((kt & 1) * 32768);
    const unsigned nbR = bbO ^ 32768u;
    const int ktB = (kt + 1 < 32) ? kt + 1 : 31;
    const int ktA = (kt + 2 < 32) ? kt + 2 : 31;
    const char* gBn = gB + ktB * 128;
    const char* gAn = gA + ktA * 128;

    // -------- phase 0: A[mh0] + B[nh0] reads; stage B0(kt+1); MFMA mh0 x nh0
#pragma unroll
    for (int i = 0; i < 4; ++i) {
      DSR(a0[i][0], ldsb + bbO + aR0 + (unsigned)(i * 2048));
      DSR(a0[i][1], ldsb + bbO + aR1 + (unsigned)(i * 2048));
    }
#pragma unroll
    for (int j = 0; j < 2; ++j) {
      DSR(bq[j][0], ldsb + bbO + bR0 + (unsigned)(j * 2048));
      DSR(bq[j][1], ldsb + bbO + bR1 + (unsigned)(j * 2048));
    }
    STG(gBn, 65536u + nbR + w1024);
    __builtin_amdgcn_s_barrier();
    asm volatile("s_waitcnt lgkmcnt(0)" ::: "memory");
    __builtin_amdgcn_sched_barrier(0);
    __builtin_amdgcn_s_setprio(1);
#pragma unroll
    for (int i = 0; i < 4; ++i)
#pragma unroll
      for (int j = 0; j < 2; ++j) {
        acc[i][j] = __builtin_amdgcn_mfma_f32_16x16x32_bf16(a0[i][0], bq[j][0], acc[i][j], 0, 0, 0);
        acc[i][j] = __builtin_amdgcn_mfma_f32_16x16x32_bf16(a0[i][1], bq[j][1], acc[i][j], 0, 0, 0);
      }
    __builtin_amdgcn_s_setprio(0);
    __builtin_amdgcn_s_barrier();

    // -------- phase 1: A[mh1] reads; stage B1(kt+1); MFMA mh1 x nh0
#pragma unroll
    for (int i = 0; i < 4; ++i) {
      DSR(a1[i][0], ldsb + bbO + aR0 + (unsigned)((4 + i) * 2048));
      DSR(a1[i][1], ldsb + bbO + aR1 + (unsigned)((4 + i) * 2048));
    }
    STG(gBn + 524288, 81920u + nbR + w1024);
    __builtin_amdgcn_s_barrier();
    asm volatile("s_waitcnt lgkmcnt(0)" ::: "memory");
    __builtin_amdgcn_sched_barrier(0);
    __builtin_amdgcn_s_setprio(1);
#pragma unroll
    for (int i = 0; i < 4; ++i)
#pragma unroll
      for (int j = 0; j < 2; ++j) {
        acc[4 + i][j] = __builtin_amdgcn_mfma_f32_16x16x32_bf16(a1[i][0], bq[j][0], acc[4 + i][j], 0, 0, 0);
        acc[4 + i][j] = __builtin_amdgcn_mfma_f32_16x16x32_bf16(a1[i][1], bq[j][1], acc[4 + i][j], 0, 0, 0);
      }
    __builtin_amdgcn_s_setprio(0);
    __builtin_amdgcn_s_barrier();

    // -------- phase 2: B[nh1] reads (reuse bq); stage A0(kt+2); MFMA mh0 x nh1
#pragma unroll
    for (int j = 0; j < 2; ++j) {
      DSR(bq[j][0], ldsb + bbO + bR0 + (unsigned)((2 + j) * 2048));
      DSR(bq[j][1], ldsb + bbO + bR1 + (unsigned)((2 + j) * 2048));
    }
    STG(gAn, bbO + w1024);
    __builtin_amdgcn_s_barrier();
    asm volatile("s_waitcnt lgkmcnt(0)" ::: "memory");
    __builtin_amdgcn_sched_barrier(0);
    __builtin_amdgcn_s_setprio(1);
#pragma unroll
    for (int i = 0; i < 4; ++i)
#pragma unroll
      for (int j = 0; j < 2; ++j) {
        acc[i][2 + j] = __builtin_amdgcn_mfma_f32_16x16x32_bf16(a0[i][0], bq[j][0], acc[i][2 + j], 0, 0, 0);
        acc[i][2 + j] = __builtin_amdgcn_mfma_f32_16x16x32_bf16(a0[i][1], bq[j][1], acc[i][2 + j], 0, 0, 0);
      }
    __builtin_amdgcn_s_setprio(0);
    __builtin_amdgcn_s_barrier();

    // -------- phase 3: stage A1(kt+2); MFMA mh1 x nh1; counted vmcnt(4)
    STG(gAn + 524288, bbO + 16384u + w1024);
    __builtin_amdgcn_s_barrier();
    __builtin_amdgcn_s_setprio(1);
#pragma unroll
    for (int i = 0; i < 4; ++i)
#pragma unroll
      for (int j = 0; j < 2; ++j) {
        acc[4 + i][2 + j] = __builtin_amdgcn_mfma_f32_16x16x32_bf16(a1[i][0], bq[j][0], acc[4 + i][2 + j], 0, 0, 0);
        acc[4 + i][2 + j] = __builtin_amdgcn_mfma_f32_16x16x32_bf16(a1[i][1], bq[j][1], acc[4 + i][2 + j], 0, 0, 0);
      }
    __builtin_amdgcn_s_setprio(0);
    asm volatile("s_waitcnt vmcnt(4)" ::: "memory");
    __builtin_amdgcn_sched_barrier(0);
    __builtin_amdgcn_s_barrier();
  }
#undef STG
  asm volatile("s_waitcnt vmcnt(0)" ::: "memory");  // drain tail stages before exit

  // epilogue: C/D layout col=lane&15, row=(lane>>4)*4+reg  [m89/m91]
  const int m0 = by * 256 + wmw + ((lane >> 4) << 2);
  const int n0 = bx * 256 + wnw + (lane & 15);
  float bc[4];
#pragma unroll
  for (int j = 0; j < 4; ++j) bc[j] = bias[n0 + j * 16];
#pragma unroll
  for (int i = 0; i < 8; ++i)
#pragma unroll
    for (int r = 0; r < 4; ++r) {
      const int m = m0 + i * 16 + r;
      const float sm = S[m];
#pragma unroll
      for (int j = 0; j < 4; ++j)
        Out[(size_t)m * 8192 + n0 + j * 16] = acc[i][j][r] + sm * bc[j];
    }
}

// ---------------------------------------------------------------------------
// launch
// ---------------------------------------------------------------------------
extern "C" void kernel_launch(void* const* d_in, const int* in_sizes, int n_in,
                              void* d_out, int out_size, void* d_ws,
                              size_t ws_size, hipStream_t stream) {
  (void)in_sizes; (void)n_in; (void)out_size; (void)ws_size;
  const float* x       = (const float*)d_in[0];  // (B,T,IN)
  const float* combine = (const float*)d_in[1];  // (B,T,E,C)
  const float* mask    = (const float*)d_in[2];  // (B,T,E,C)
  const float* weight  = (const float*)d_in[3];  // (OUT,IN)
  const float* bias    = (const float*)d_in[4];  // (OUT,)
  float* out = (float*)d_out;                    // (B,T,OUT) fp32

  // workspace layout (~105 MB)
  char* ws = (char*)d_ws;
  unsigned short* W2      = (unsigned short*)ws;                    // 32 MB
  unsigned short* comb_bf = (unsigned short*)(ws + 33554432);       // 16 MB
  float*          S       = (float*)(ws + 50331648);                // 16 KB
  unsigned short* xT      = (unsigned short*)(ws + 51380224);       // 16 MB
  unsigned short* maskT   = (unsigned short*)(ws + 68157440);       // 16 MB
  unsigned short* xdT     = (unsigned short*)(ws + 84934656);       //  8 MB
  unsigned short* zbuf    = (unsigned short*)(ws + 93323264);       // 16 MB

  // 0) all layout/dtype prep in ONE launch
  prep<<<16384, 256, 0, stream>>>(x, mask, combine, weight, xT, maskT,
                                  comb_bf, S, W2);

  // 1) xdT[b,e,i,c] = sum_t xT[b,e,i,t] * maskT[b,e,c,t]
  gemm_bt<0><<<dim3(4, 4, 16), 512, 0, stream>>>(
      xT, maskT, (void*)xdT, nullptr, nullptr, 1024, 1024, 512, 1024,
      4, 2097152L, 524288L, 2097152L, 524288L, 1048576L, 262144L);

  // 2) z[b,t,(e,i)] = sum_c comb_bf[b,t,e,c] * xdT[b,e,i,c]
  gemm_bt<0><<<dim3(4, 8, 16), 512, 0, stream>>>(
      comb_bf, xdT, (void*)zbuf, nullptr, nullptr, 2048, 512, 2048, 512,
      4, 2097152L, 512L, 1048576L, 262144L, 2097152L, 512L);

  // 3) out[m,o] = sum_{(e,i)} z[m,(e,i)] * W2[o,(e,i)] + S[m]*bias[o]
  //    M=4096 N=8192 K=2048 — 256^2 round-0 schedule, plain stores
  gemm256<<<dim3(512), 512, 0, stream>>>(zbuf, W2, out, bias, S);
}

// Round 7
// 402.455 us; speedup vs baseline: 1.0661x; 1.0116x over previous
//
#include <hip/hip_runtime.h>

// Problem constants (from reference setup_inputs)
#define B_   4
#define T_   1024
#define E_   4
#define C_   512
#define IN_  2048
#define OUT_ 8192
#define EI_  512   // expert in-features = IN_/E_

typedef float f32x4 __attribute__((ext_vector_type(4)));
typedef __bf16 bf16x8 __attribute__((ext_vector_type(8)));
typedef unsigned short ushort8 __attribute__((ext_vector_type(8)));

__device__ __forceinline__ unsigned short f32_bf16(float f) {
  unsigned int u = __float_as_uint(f);
  u += 0x7FFFu + ((u >> 16) & 1u);   // round-to-nearest-even (finite inputs)
  return (unsigned short)(u >> 16);
}

__device__ __forceinline__ void gl2lds16(const void* g, void* l) {
  __builtin_amdgcn_global_load_lds(
      (const __attribute__((address_space(1))) void*)g,
      (__attribute__((address_space(3))) void*)l, 16, 0, 0);
}

#define DSR(dst, addr) do { f32x4 _t_; \
    asm volatile("ds_read_b128 %0, %1" : "=v"(_t_) : "v"(addr)); \
    dst = __builtin_bit_cast(bf16x8, _t_); } while (0)

// ---------------------------------------------------------------------------
// Fused prep: one launch, three independent jobs selected by blockIdx range.
//  [0,4096)    : transpose-convert x/mask (B,T,2048) fp32 -> (B,4,512,T) bf16
//  [4096,8192) : combine fp32->bf16 + row-sum S
//  [8192,16384): weight permute w[e,o,i] -> W2[o, e*512+i] bf16
// ---------------------------------------------------------------------------
__global__ __launch_bounds__(256)
void prep(const float* __restrict__ xsrc, const float* __restrict__ msrc,
          const float* __restrict__ combine, const float* __restrict__ weight,
          unsigned short* __restrict__ xdst, unsigned short* __restrict__ mdst,
          unsigned short* __restrict__ comb_bf, float* __restrict__ S,
          unsigned short* __restrict__ W2) {
  const int bid = blockIdx.x;
  const int u = threadIdx.x;
  if (bid < 4096) {
    // ---- transpose_cvt body ----
    __shared__ float tile[64][65];
    const int z = bid >> 9;             // 0..7
    const int which = z >> 2;
    const int b = z & 3;
    const int rem = bid & 511;
    const int t0 = (rem >> 5) * 64;
    const int k0 = (rem & 31) * 64;
    const float* src = which ? msrc : xsrc;
    unsigned short* dst = which ? mdst : xdst;
    const int lrow = u >> 4;
    const int lcol = (u & 15) * 4;
    const float* s = src + (size_t)b * (T_ * 2048) + (size_t)t0 * 2048 + k0;
#pragma unroll
    for (int r = 0; r < 4; r++) {
      float4 v = *(const float4*)(s + (size_t)(lrow + 16 * r) * 2048 + lcol);
      tile[lrow + 16 * r][lcol]     = v.x;
      tile[lrow + 16 * r][lcol + 1] = v.y;
      tile[lrow + 16 * r][lcol + 2] = v.z;
      tile[lrow + 16 * r][lcol + 3] = v.w;
    }
    __syncthreads();
    const int kr = u >> 2;
    const int tq = (u & 3) * 8;
    const int kg = k0 + kr;
    const int e  = kg >> 9;
    const int kl = kg & 511;
    unsigned short* d = dst + (((size_t)b * 4 + e) * 512 + kl) * 1024 + t0 + tq;
#pragma unroll
    for (int s8 = 0; s8 < 2; s8++) {
      ushort8 rr;
#pragma unroll
      for (int j = 0; j < 8; j++) rr[j] = f32_bf16(tile[tq + s8 * 32 + j][kr]);
      *(ushort8*)(d + s8 * 32) = rr;
    }
  } else if (bid < 8192) {
    // ---- cvt_combine_rowsum body ----
    __shared__ float red[256];
    const int row = bid - 4096;
    const float4* p = (const float4*)(combine + (size_t)row * 2048) + (size_t)u * 2;
    float4 a = p[0], b = p[1];
    ushort8 r;
    r[0] = f32_bf16(a.x); r[1] = f32_bf16(a.y);
    r[2] = f32_bf16(a.z); r[3] = f32_bf16(a.w);
    r[4] = f32_bf16(b.x); r[5] = f32_bf16(b.y);
    r[6] = f32_bf16(b.z); r[7] = f32_bf16(b.w);
    *((ushort8*)(comb_bf + (size_t)row * 2048) + u) = r;
    float s = (a.x + a.y + a.z + a.w) + (b.x + b.y + b.z + b.w);
    red[u] = s;
    __syncthreads();
#pragma unroll
    for (int st = 128; st > 0; st >>= 1) {
      if (u < st) red[u] += red[u + st];
      __syncthreads();
    }
    if (u == 0) S[row] = red[0];
  } else {
    // ---- permute_w body ----
    const int tid = (bid - 8192) * 256 + u;
    const int i8 = tid & 63;
    const int e  = (tid >> 6) & 3;
    const int o  = tid >> 8;
    const float* s = weight + (size_t)e * 4194304 + (size_t)o * 512 + i8 * 8;
    float4 a = *(const float4*)s;
    float4 b = *(const float4*)(s + 4);
    ushort8 r;
    r[0] = f32_bf16(a.x); r[1] = f32_bf16(a.y);
    r[2] = f32_bf16(a.z); r[3] = f32_bf16(a.w);
    r[4] = f32_bf16(b.x); r[5] = f32_bf16(b.y);
    r[6] = f32_bf16(b.z); r[7] = f32_bf16(b.w);
    *(ushort8*)(W2 + (size_t)o * 2048 + e * 512 + i8 * 8) = r;
  }
}

// ---------------------------------------------------------------------------
// gemm_bt: 128x128 tile, BK=32, 512 threads / 8 waves (2 waves/SIMD).
// Per-wave output 64x32 (2M x 4N wave grid). Triple-buffered, counted
// vmcnt(2): stage t+2 -> buf[(t+2)%3] each iter, drain t+1's pair at the
// bottom -> ~2-iteration prefetch distance. (Unchanged from round 6.)
// ---------------------------------------------------------------------------
template <int MODE>
__global__ __launch_bounds__(512, 2)
void gemm_bt(const unsigned short* __restrict__ A,
             const unsigned short* __restrict__ Bm,
             void* __restrict__ Out, const float* __restrict__ bias,
             const float* __restrict__ S,
             int lda, int ldb, int ldo, int K, int Ediv,
             long sAb, long sAe, long sBb, long sBe, long sOb, long sOe) {
  // A bufs: [0, 24576) = 3 x 8KB ; B bufs: [24576, 49152)
  __shared__ __align__(16) char ldsRaw[49152];
  char* ldsg = ldsRaw;
  const unsigned ldsb =
      (unsigned)(unsigned long long)(__attribute__((address_space(3))) char*)(void*)ldsRaw;

  const int u = threadIdx.x;
  const int z = blockIdx.z;
  const int zb = z / Ediv, ze = z % Ediv;
  const unsigned short* Ab = A  + zb * sAb + ze * sAe + (long)(blockIdx.y * 128) * lda;
  const unsigned short* Bb = Bm + zb * sBb + ze * sBe + (long)(blockIdx.x * 128) * ldb;

  // staging: 4 lanes per 64B row, 512 threads cover 128 rows x 32 k
  const unsigned short* gA = Ab + (long)(u >> 2) * lda + (u & 3) * 8;
  const unsigned short* gB = Bb + (long)(u >> 2) * ldb + (u & 3) * 8;

  const int w = u >> 6, lane = u & 63;
  const int wm = (w & 1) * 64, wn = (w >> 1) * 32;   // 2M x 4N wave grid
  const int fm = lane & 15, fk = (lane >> 4) * 8;
  const unsigned aF = (unsigned)((wm + fm) * 64 + fk * 2);           // byte off in A buf
  const unsigned bF = 24576u + (unsigned)((wn + fm) * 64 + fk * 2);  // byte off (B region)
  const unsigned u16 = (unsigned)(u * 16);

  f32x4 acc[4][2] = {};

  const int nt = K / 32;   // >= 16 for all uses
#define STGBT(buf, kk) do { \
    gl2lds16(gA + (kk) * 32, ldsg + (buf) * 8192 + u16); \
    gl2lds16(gB + (kk) * 32, ldsg + 24576 + (buf) * 8192 + u16); } while (0)

  // prologue: tiles 0,1 -> bufs 0,1; wait tile 0 landed (leave tile 1's 2)
  STGBT(0, 0);
  STGBT(1, 1);
  asm volatile("s_waitcnt vmcnt(2)" ::: "memory");
  __builtin_amdgcn_s_barrier();

  int cur = 0, pre = 2;
  for (int t = 0; t < nt; ++t) {
    bf16x8 af[4], bfv[2];
    const unsigned cb = (unsigned)(cur * 8192);
#pragma unroll
    for (int i = 0; i < 4; i++) DSR(af[i], ldsb + cb + aF + (unsigned)(i * 1024));
#pragma unroll
    for (int j = 0; j < 2; j++) DSR(bfv[j], ldsb + cb + bF + (unsigned)(j * 1024));
    const int kk = (t + 2 < nt) ? t + 2 : nt - 1;   // clamp source only
    STGBT(pre, kk);
    asm volatile("s_waitcnt lgkmcnt(0)" ::: "memory");
    __builtin_amdgcn_sched_barrier(0);
    __builtin_amdgcn_s_setprio(1);
#pragma unroll
    for (int i = 0; i < 4; i++)
#pragma unroll
      for (int j = 0; j < 2; j++)
        acc[i][j] = __builtin_amdgcn_mfma_f32_16x16x32_bf16(af[i], bfv[j],
                                                            acc[i][j], 0, 0, 0);
    __builtin_amdgcn_s_setprio(0);
    asm volatile("s_waitcnt vmcnt(2)" ::: "memory");  // drain t+1's stage
    __builtin_amdgcn_sched_barrier(0);
    __builtin_amdgcn_s_barrier();
    cur = (cur == 2) ? 0 : cur + 1;
    pre = (pre == 2) ? 0 : pre + 1;
  }
#undef STGBT
  asm volatile("s_waitcnt vmcnt(0)" ::: "memory");  // drain tail stages

  const long ob = zb * sOb + ze * sOe;
  const int em0 = blockIdx.y * 128 + wm + ((lane >> 4) << 2);
  const int en0 = blockIdx.x * 128 + wn + fm;
  float bcol[2];
  if (MODE == 1) {
#pragma unroll
    for (int j = 0; j < 2; j++) bcol[j] = bias[en0 + j * 16];
  }
#pragma unroll
  for (int i = 0; i < 4; i++)
#pragma unroll
    for (int r = 0; r < 4; r++) {
      const int m = em0 + i * 16 + r;
      const float sm = (MODE == 1) ? S[m] : 0.0f;
#pragma unroll
      for (int j = 0; j < 2; j++) {
        const long off = ob + (long)m * ldo + en0 + j * 16;
        if (MODE == 1)
          ((float*)Out)[off] = acc[i][j][r] + sm * bcol[j];
        else
          ((unsigned short*)Out)[off] = f32_bf16(acc[i][j][r]);
      }
    }
}

// ---------------------------------------------------------------------------
// gemm256: 256x256 tile, BK=64, 8 waves, 4-phase/K-tile — round-0 schedule.
// D = A·B^T + S[m]*bias[n].  M=4096 N=8192 K=2048.
//
// THIS ROUND: XCD COLUMN-STRIPE rasterization. Old swizzle gave each XCD a
// 2by x 32bx stripe -> per-XCD L2-miss = A 2MB + B 32MB = 34MB x 8 = 272MB
// (matches measured FETCH_SIZE 270.7MB). New: each XCD owns 4bx x 16by
// (full M): B-stripe 4MB (L2-resident), A 16MB streamed with bx-fast visit
// order (A-tile L2-cached across its 4 bx) -> model ~20MB x 8 = 160MB.
// bx = (bid&7)*4 + ((bid>>3)&3), by = bid>>5  — bijective (8*4*16 = 512).
//
// LDS: A buf0 [0,32K) | A buf1 [32K,64K) | B buf0 [64K,96K) | B buf1 [96K,128K)
// XOR swizzle byte ^= ((row&7)<<4); gl2lds writes linear, inverse swz on src.
//   p0: DSR a0(8)+bq nh0(4); STG B0(kt+1)->nb ; MFMA mh0 x nh0
//   p1: DSR a1(8)          ; STG B1(kt+1)->nb ; MFMA mh1 x nh0
//   p2: DSR bq nh1(4)      ; STG A0(kt+2)->bb ; MFMA mh0 x nh1
//   p3:                      STG A1(kt+2)->bb ; MFMA mh1 x nh1; vmcnt(4)
// ---------------------------------------------------------------------------
__global__ __launch_bounds__(512, 2)
void gemm256(const unsigned short* __restrict__ A,
             const unsigned short* __restrict__ Bm,
             float* __restrict__ Out,
             const float* __restrict__ bias,
             const float* __restrict__ S) {
  __shared__ __align__(16) unsigned short lds[65536];  // 128 KiB
  char* ldsg = (char*)lds;
  const unsigned ldsb =
      (unsigned)(unsigned long long)(__attribute__((address_space(3))) char*)(void*)lds;

  const int bid = blockIdx.x;
  const int bx = (bid & 7) * 4 + ((bid >> 3) & 3);   // N tile 0..31 (4/XCD)
  const int by = bid >> 5;                           // M tile 0..15 (all/XCD)

  const int u = threadIdx.x;
  const int w = u >> 6, lane = u & 63;
  const unsigned w1024 = (unsigned)(w * 1024);
  const int wmw = (w >> 2) * 128;      // wave M offset in tile
  const int wnw = (w & 3) * 64;        // wave N offset in tile
  const int fm = lane & 15;

  // read-side swizzled column bases (byte ^= ((row&7)<<4); row&7 == fm&7)
  const unsigned hi16  = (unsigned)(((lane >> 4) & 3) * 16);
  const unsigned xorv  = (unsigned)((fm & 7) << 4);
  const unsigned colS0 = hi16 ^ xorv;
  const unsigned aR0 = (unsigned)((wmw + fm) * 128) + colS0;
  const unsigned aR1 = aR0 ^ 64u;                     // k-step 1 (+32 elems)
  const unsigned bR0 = 65536u + (unsigned)((wnw + fm) * 128) + colS0;
  const unsigned bR1 = bR0 ^ 64u;

  // stage-side: LDS dest linear (u*16B within half-tile); source pre-swizzled.
  const int srr = w * 8 + (lane >> 3);
  const unsigned swzS = (unsigned)((((lane & 7) ^ ((lane >> 3) & 7)) << 4));
  const char* gA = (const char*)(A  + (size_t)(by * 256) * 2048) + (size_t)srr * 4096 + swzS;
  const char* gB = (const char*)(Bm + (size_t)(bx * 256) * 2048) + (size_t)srr * 4096 + swzS;

  // one STG = one half-tile (128 rows x 128B): 2 x global_load_lds dwordx4 / thread
#define STG(gsrc, loff) do { \
    gl2lds16((gsrc), ldsg + (loff)); \
    gl2lds16((gsrc) + 262144, ldsg + (loff) + 8192); } while (0)

  // prologue: kt0 {A0,A1,B0,B1} -> buf0; kt1 {A0,A1} -> buf1; wait kt0 landed
  STG(gA,                    0u + w1024);
  STG(gA + 524288,       16384u + w1024);
  STG(gB,                65536u + w1024);
  STG(gB + 524288,       81920u + w1024);
  STG(gA + 128,          32768u + w1024);
  STG(gA + 128 + 524288, 49152u + w1024);
  asm volatile("s_waitcnt vmcnt(4)" ::: "memory");
  __builtin_amdgcn_s_barrier();

  f32x4 acc[8][4] = {};
  bf16x8 a0[4][2], a1[4][2], bq[2][2];

  for (int kt = 0; kt < 32; ++kt) {
    const unsigned bbO = (unsigned)((kt & 1) * 32768);
    const unsigned nbR = bbO ^ 32768u;
    const int ktB = (kt + 1 < 32) ? kt + 1 : 31;
    const int ktA = (kt + 2 < 32) ? kt + 2 : 31;
    const char* gBn = gB + ktB * 128;
    const char* gAn = gA + ktA * 128;

    // -------- phase 0: A[mh0] + B[nh0] reads; stage B0(kt+1); MFMA mh0 x nh0
#pragma unroll
    for (int i = 0; i < 4; ++i) {
      DSR(a0[i][0], ldsb + bbO + aR0 + (unsigned)(i * 2048));
      DSR(a0[i][1], ldsb + bbO + aR1 + (unsigned)(i * 2048));
    }
#pragma unroll
    for (int j = 0; j < 2; ++j) {
      DSR(bq[j][0], ldsb + bbO + bR0 + (unsigned)(j * 2048));
      DSR(bq[j][1], ldsb + bbO + bR1 + (unsigned)(j * 2048));
    }
    STG(gBn, 65536u + nbR + w1024);
    __builtin_amdgcn_s_barrier();
    asm volatile("s_waitcnt lgkmcnt(0)" ::: "memory");
    __builtin_amdgcn_sched_barrier(0);
    __builtin_amdgcn_s_setprio(1);
#pragma unroll
    for (int i = 0; i < 4; ++i)
#pragma unroll
      for (int j = 0; j < 2; ++j) {
        acc[i][j] = __builtin_amdgcn_mfma_f32_16x16x32_bf16(a0[i][0], bq[j][0], acc[i][j], 0, 0, 0);
        acc[i][j] = __builtin_amdgcn_mfma_f32_16x16x32_bf16(a0[i][1], bq[j][1], acc[i][j], 0, 0, 0);
      }
    __builtin_amdgcn_s_setprio(0);
    __builtin_amdgcn_s_barrier();

    // -------- phase 1: A[mh1] reads; stage B1(kt+1); MFMA mh1 x nh0
#pragma unroll
    for (int i = 0; i < 4; ++i) {
      DSR(a1[i][0], ldsb + bbO + aR0 + (unsigned)((4 + i) * 2048));
      DSR(a1[i][1], ldsb + bbO + aR1 + (unsigned)((4 + i) * 2048));
    }
    STG(gBn + 524288, 81920u + nbR + w1024);
    __builtin_amdgcn_s_barrier();
    asm volatile("s_waitcnt lgkmcnt(0)" ::: "memory");
    __builtin_amdgcn_sched_barrier(0);
    __builtin_amdgcn_s_setprio(1);
#pragma unroll
    for (int i = 0; i < 4; ++i)
#pragma unroll
      for (int j = 0; j < 2; ++j) {
        acc[4 + i][j] = __builtin_amdgcn_mfma_f32_16x16x32_bf16(a1[i][0], bq[j][0], acc[4 + i][j], 0, 0, 0);
        acc[4 + i][j] = __builtin_amdgcn_mfma_f32_16x16x32_bf16(a1[i][1], bq[j][1], acc[4 + i][j], 0, 0, 0);
      }
    __builtin_amdgcn_s_setprio(0);
    __builtin_amdgcn_s_barrier();

    // -------- phase 2: B[nh1] reads (reuse bq); stage A0(kt+2); MFMA mh0 x nh1
#pragma unroll
    for (int j = 0; j < 2; ++j) {
      DSR(bq[j][0], ldsb + bbO + bR0 + (unsigned)((2 + j) * 2048));
      DSR(bq[j][1], ldsb + bbO + bR1 + (unsigned)((2 + j) * 2048));
    }
    STG(gAn, bbO + w1024);
    __builtin_amdgcn_s_barrier();
    asm volatile("s_waitcnt lgkmcnt(0)" ::: "memory");
    __builtin_amdgcn_sched_barrier(0);
    __builtin_amdgcn_s_setprio(1);
#pragma unroll
    for (int i = 0; i < 4; ++i)
#pragma unroll
      for (int j = 0; j < 2; ++j) {
        acc[i][2 + j] = __builtin_amdgcn_mfma_f32_16x16x32_bf16(a0[i][0], bq[j][0], acc[i][2 + j], 0, 0, 0);
        acc[i][2 + j] = __builtin_amdgcn_mfma_f32_16x16x32_bf16(a0[i][1], bq[j][1], acc[i][2 + j], 0, 0, 0);
      }
    __builtin_amdgcn_s_setprio(0);
    __builtin_amdgcn_s_barrier();

    // -------- phase 3: stage A1(kt+2); MFMA mh1 x nh1; counted vmcnt(4)
    STG(gAn + 524288, bbO + 16384u + w1024);
    __builtin_amdgcn_s_barrier();
    __builtin_amdgcn_s_setprio(1);
#pragma unroll
    for (int i = 0; i < 4; ++i)
#pragma unroll
      for (int j = 0; j < 2; ++j) {
        acc[4 + i][2 + j] = __builtin_amdgcn_mfma_f32_16x16x32_bf16(a1[i][0], bq[j][0], acc[4 + i][2 + j], 0, 0, 0);
        acc[4 + i][2 + j] = __builtin_amdgcn_mfma_f32_16x16x32_bf16(a1[i][1], bq[j][1], acc[4 + i][2 + j], 0, 0, 0);
      }
    __builtin_amdgcn_s_setprio(0);
    asm volatile("s_waitcnt vmcnt(4)" ::: "memory");
    __builtin_amdgcn_sched_barrier(0);
    __builtin_amdgcn_s_barrier();
  }
#undef STG
  asm volatile("s_waitcnt vmcnt(0)" ::: "memory");  // drain tail stages before exit

  // epilogue: C/D layout col=lane&15, row=(lane>>4)*4+reg  [m89/m91]
  const int m0 = by * 256 + wmw + ((lane >> 4) << 2);
  const int n0 = bx * 256 + wnw + (lane & 15);
  float bc[4];
#pragma unroll
  for (int j = 0; j < 4; ++j) bc[j] = bias[n0 + j * 16];
#pragma unroll
  for (int i = 0; i < 8; ++i)
#pragma unroll
    for (int r = 0; r < 4; ++r) {
      const int m = m0 + i * 16 + r;
      const float sm = S[m];
#pragma unroll
      for (int j = 0; j < 4; ++j)
        Out[(size_t)m * 8192 + n0 + j * 16] = acc[i][j][r] + sm * bc[j];
    }
}

// ---------------------------------------------------------------------------
// launch
// ---------------------------------------------------------------------------
extern "C" void kernel_launch(void* const* d_in, const int* in_sizes, int n_in,
                              void* d_out, int out_size, void* d_ws,
                              size_t ws_size, hipStream_t stream) {
  (void)in_sizes; (void)n_in; (void)out_size; (void)ws_size;
  const float* x       = (const float*)d_in[0];  // (B,T,IN)
  const float* combine = (const float*)d_in[1];  // (B,T,E,C)
  const float* mask    = (const float*)d_in[2];  // (B,T,E,C)
  const float* weight  = (const float*)d_in[3];  // (OUT,IN)
  const float* bias    = (const float*)d_in[4];  // (OUT,)
  float* out = (float*)d_out;                    // (B,T,OUT) fp32

  // workspace layout (~105 MB)
  char* ws = (char*)d_ws;
  unsigned short* W2      = (unsigned short*)ws;                    // 32 MB
  unsigned short* comb_bf = (unsigned short*)(ws + 33554432);       // 16 MB
  float*          S       = (float*)(ws + 50331648);                // 16 KB
  unsigned short* xT      = (unsigned short*)(ws + 51380224);       // 16 MB
  unsigned short* maskT   = (unsigned short*)(ws + 68157440);       // 16 MB
  unsigned short* xdT     = (unsigned short*)(ws + 84934656);       //  8 MB
  unsigned short* zbuf    = (unsigned short*)(ws + 93323264);       // 16 MB

  // 0) all layout/dtype prep in ONE launch
  prep<<<16384, 256, 0, stream>>>(x, mask, combine, weight, xT, maskT,
                                  comb_bf, S, W2);

  // 1) xdT[b,e,i,c] = sum_t xT[b,e,i,t] * maskT[b,e,c,t]
  gemm_bt<0><<<dim3(4, 4, 16), 512, 0, stream>>>(
      xT, maskT, (void*)xdT, nullptr, nullptr, 1024, 1024, 512, 1024,
      4, 2097152L, 524288L, 2097152L, 524288L, 1048576L, 262144L);

  // 2) z[b,t,(e,i)] = sum_c comb_bf[b,t,e,c] * xdT[b,e,i,c]
  gemm_bt<0><<<dim3(4, 8, 16), 512, 0, stream>>>(
      comb_bf, xdT, (void*)zbuf, nullptr, nullptr, 2048, 512, 2048, 512,
      4, 2097152L, 512L, 1048576L, 262144L, 2097152L, 512L);

  // 3) out[m,o] = sum_{(e,i)} z[m,(e,i)] * W2[o,(e,i)] + S[m]*bias[o]
  //    M=4096 N=8192 K=2048 — round-0 schedule + XCD column-stripe raster
  gemm256<<<dim3(512), 512, 0, stream>>>(zbuf, W2, out, bias, S);
}